// Round 2
// baseline (2952.995 us; speedup 1.0000x reference)
//
#include <hip/hip_runtime.h>

#define N_NODES 50000
#define N_EDGES 400000
#define DH 128
#define N_GRAPHS 256

typedef __bf16 bf16x8 __attribute__((ext_vector_type(8)));
typedef float f32x4 __attribute__((ext_vector_type(4)));

#define DEV __device__ __forceinline__

DEV unsigned short f2bf(float f) {
  union { float f; unsigned int i; } v; v.f = f;
  unsigned int x = v.i;
  unsigned int r = (x + 0x7fffu + ((x >> 16) & 1u)) >> 16;
  return (unsigned short)r;
}

DEV void atomicMaxFloat(float* addr, float val) {
  int vi = __float_as_int(val);
  if (vi >= 0) atomicMax((int*)addr, vi);
  else atomicMin((unsigned int*)addr, (unsigned int)vi);
}

// ---------------- weight repack: WT[o*128+i] = bf16(W[i*128+o]) --------------
struct WPtrs { const float* w[12]; };

__global__ void repack_kernel(WPtrs wp, unsigned short* __restrict__ WT) {
  int mat = blockIdx.y;
  int idx = blockIdx.x * 256 + threadIdx.x;   // 0..16383
  int i = idx >> 7, o = idx & 127;
  WT[mat * 16384 + o * 128 + i] = f2bf(wp.w[mat][i * 128 + o]);
}

// ---------------- fp32 -> bf16 convert (layer-0 x) ---------------------------
__global__ void f32_to_bf16(const float* __restrict__ in, unsigned short* __restrict__ out,
                            int total4) {
  int i = blockIdx.x * 256 + threadIdx.x;
  if (i >= total4) return;
  float4 v = *reinterpret_cast<const float4*>(in + i * 4);
  ushort4 o;
  o.x = f2bf(v.x); o.y = f2bf(v.y); o.z = f2bf(v.z); o.w = f2bf(v.w);
  *reinterpret_cast<ushort4*>(out + i * 4) = o;
}

// ---------------- fused projection GEMM: Y = X @ W + b  ----------------------
// X: [N,128] bf16 row-major.  WT: [128(out),128(in)] bf16.  Y: [N,128] f32.
// blockIdx.y in 0..3 selects {Q,K,V,S->H}.
struct GemmOut { float* Y[4]; const float* bias[4]; };

#define LDP 136   // padded LDS row stride (bf16 elems); breaks 256B-stride conflicts

__global__ __launch_bounds__(256) void gemm_proj(
    const unsigned short* __restrict__ X,
    const unsigned short* __restrict__ WT4,   // 4 matrices of 16384 contiguous
    GemmOut go, int N)
{
  __shared__ __align__(16) unsigned short xs[64 * LDP];
  __shared__ __align__(16) unsigned short wsh[128 * LDP];

  const int proj = blockIdx.y;
  const unsigned short* WT = WT4 + proj * 16384;
  float* __restrict__ Y = go.Y[proj];
  const float* __restrict__ bias = go.bias[proj];

  const int t = threadIdx.x;
  const int rowBase = blockIdx.x * 64;

  // stage WT (128x128 bf16) into LDS, padded
#pragma unroll
  for (int j = 0; j < 8; ++j) {
    int v = t + 256 * j;            // 0..2047 vectors of 8 bf16
    int o = v >> 4;
    int ig = (v & 15) * 8;
    uint4 val = *reinterpret_cast<const uint4*>(WT + o * 128 + ig);
    *reinterpret_cast<uint4*>(&wsh[o * LDP + ig]) = val;
  }
  // stage X tile (64x128 bf16) into LDS, padded; zero-fill OOB rows
#pragma unroll
  for (int j = 0; j < 4; ++j) {
    int v = t + 256 * j;            // 0..1023
    int r = v >> 4;
    int ig = (v & 15) * 8;
    int grow = rowBase + r;
    uint4 val = make_uint4(0u, 0u, 0u, 0u);
    if (grow < N) val = *reinterpret_cast<const uint4*>(X + grow * 128 + ig);
    *reinterpret_cast<uint4*>(&xs[r * LDP + ig]) = val;
  }
  __syncthreads();

  const int wave = t >> 6;
  const int lane = t & 63;
  const int ln16 = lane & 15;
  const int quad = lane >> 4;
  const int r0 = wave * 16;

  f32x4 acc[8] = {};

#pragma unroll
  for (int kk = 0; kk < 4; ++kk) {
    bf16x8 a = *reinterpret_cast<const bf16x8*>(&xs[(r0 + ln16) * LDP + kk * 32 + quad * 8]);
#pragma unroll
    for (int ct = 0; ct < 8; ++ct) {
      bf16x8 b = *reinterpret_cast<const bf16x8*>(&wsh[(ct * 16 + ln16) * LDP + kk * 32 + quad * 8]);
      acc[ct] = __builtin_amdgcn_mfma_f32_16x16x32_bf16(a, b, acc[ct], 0, 0, 0);
    }
  }

#pragma unroll
  for (int ct = 0; ct < 8; ++ct) {
    int col = ct * 16 + ln16;
    float bv = bias[col];
#pragma unroll
    for (int reg = 0; reg < 4; ++reg) {
      int grow = rowBase + r0 + quad * 4 + reg;
      if (grow < N) Y[grow * 128 + col] = acc[ct][reg] + bv;
    }
  }
}

// ---------------- edge pass A: logits + segment max --------------------------
__global__ __launch_bounds__(256) void edge_logits(
    const int* __restrict__ ei, const float* __restrict__ Q,
    const float* __restrict__ K, float* __restrict__ logitw,
    float* __restrict__ mbuf, int E)
{
  int e = blockIdx.x * 8 + (threadIdx.x >> 5);
  int lane = threadIdx.x & 31;
  if (e >= E) return;
  int src = ei[e], dst = ei[E + e];
  float4 q = *reinterpret_cast<const float4*>(Q + dst * 128 + lane * 4);
  float4 k = *reinterpret_cast<const float4*>(K + src * 128 + lane * 4);
  float d = q.x * k.x + q.y * k.y + q.z * k.z + q.w * k.w;
#pragma unroll
  for (int off = 16; off; off >>= 1) d += __shfl_down(d, off, 32);
  if (lane == 0) {
    float logit = d * 0.08838834764831845f;   // 1/sqrt(128)
    logitw[e] = logit;
    atomicMaxFloat(mbuf + dst, logit);
  }
}

// ---------------- edge pass B: exp + segment sum -----------------------------
__global__ void edge_expw(const int* __restrict__ ei, float* __restrict__ logitw,
                          const float* __restrict__ mbuf, float* __restrict__ sbuf, int E)
{
  int e = blockIdx.x * 256 + threadIdx.x;
  if (e >= E) return;
  int dst = ei[E + e];
  float w = __expf(logitw[e] - mbuf[dst]);
  logitw[e] = w;
  unsafeAtomicAdd(sbuf + dst, w);
}

// ---------------- edge pass C: scatter alpha * v[src] ------------------------
__global__ __launch_bounds__(256) void edge_scatter(
    const int* __restrict__ ei, const float* __restrict__ logitw,
    const float* __restrict__ sbuf, const float* __restrict__ V,
    float* __restrict__ H, int E)
{
  int e = blockIdx.x * 8 + (threadIdx.x >> 5);
  int lane = threadIdx.x & 31;
  if (e >= E) return;
  int src = ei[e], dst = ei[E + e];
  float coef = logitw[e] / (sbuf[dst] + 1e-16f);
  float4 v = *reinterpret_cast<const float4*>(V + src * 128 + lane * 4);
  float* h = H + dst * 128 + lane * 4;
  unsafeAtomicAdd(h + 0, coef * v.x);
  unsafeAtomicAdd(h + 1, coef * v.y);
  unsafeAtomicAdd(h + 2, coef * v.z);
  unsafeAtomicAdd(h + 3, coef * v.w);
}

// ---------------- batchnorm stats --------------------------------------------
__global__ __launch_bounds__(256) void bn_stats(
    const float* __restrict__ H, float* __restrict__ bnsum,
    float* __restrict__ bnsq, int N)
{
  __shared__ float red[512];
  int t = threadIdx.x;
  int f = t & 127, half = t >> 7;
  float s = 0.f, s2 = 0.f;
  for (int row = blockIdx.x * 2 + half; row < N; row += 256) {
    float v = H[row * 128 + f];
    s += v; s2 += v * v;
  }
  red[t] = s; red[256 + t] = s2;
  __syncthreads();
  if (t < 128) {
    s = red[t] + red[t + 128];
    s2 = red[256 + t] + red[384 + t];
    unsafeAtomicAdd(bnsum + f, s);
    unsafeAtomicAdd(bnsq + f, s2);
  }
}

__global__ void bn_finalize(const float* __restrict__ bnsum, const float* __restrict__ bnsq,
                            const float* __restrict__ gamma,
                            const float* __restrict__ beta,
                            float* __restrict__ scale, float* __restrict__ shift, int N)
{
  int f = threadIdx.x;   // 128 threads
  float mean = bnsum[f] / (float)N;
  float var = bnsq[f] / (float)N - mean * mean;
  var = fmaxf(var, 0.f);
  float sc = gamma[f] * rsqrtf(var + 1e-5f);
  scale[f] = sc;
  shift[f] = beta[f] - mean * sc;
}

// ---------------- apply BN + relu, write bf16 for next layer -----------------
__global__ void bn_apply_relu(const float* __restrict__ H, const float* __restrict__ scale,
                              const float* __restrict__ shift, unsigned short* __restrict__ Xb,
                              int total)
{
  int i4 = (blockIdx.x * 256 + threadIdx.x) * 4;
  if (i4 >= total) return;
  int f = i4 & 127;
  float4 h = *reinterpret_cast<const float4*>(H + i4);
  float4 sc = *reinterpret_cast<const float4*>(scale + f);
  float4 sh = *reinterpret_cast<const float4*>(shift + f);
  ushort4 o;
  o.x = f2bf(fmaxf(h.x * sc.x + sh.x, 0.f));
  o.y = f2bf(fmaxf(h.y * sc.y + sh.y, 0.f));
  o.z = f2bf(fmaxf(h.z * sc.z + sh.z, 0.f));
  o.w = f2bf(fmaxf(h.w * sc.w + sh.w, 0.f));
  *reinterpret_cast<ushort4*>(Xb + i4) = o;
}

// ---------------- global mean pool (layer 3, fused BN+relu) ------------------
__global__ __launch_bounds__(256) void pool_kernel(
    const float* __restrict__ H, const float* __restrict__ scale,
    const float* __restrict__ shift, const int* __restrict__ batch,
    float* __restrict__ pooled, float* __restrict__ cnt, int N)
{
  int n = blockIdx.x * 8 + (threadIdx.x >> 5);
  int lane = threadIdx.x & 31;
  if (n >= N) return;
  int g = batch[n];
  int f = lane * 4;
  float4 h = *reinterpret_cast<const float4*>(H + n * 128 + f);
  float4 sc = *reinterpret_cast<const float4*>(scale + f);
  float4 sh = *reinterpret_cast<const float4*>(shift + f);
  float* p = pooled + g * 128 + f;
  unsafeAtomicAdd(p + 0, fmaxf(h.x * sc.x + sh.x, 0.f));
  unsafeAtomicAdd(p + 1, fmaxf(h.y * sc.y + sh.y, 0.f));
  unsafeAtomicAdd(p + 2, fmaxf(h.z * sc.z + sh.z, 0.f));
  unsafeAtomicAdd(p + 3, fmaxf(h.w * sc.w + sh.w, 0.f));
  if (lane == 0) unsafeAtomicAdd(cnt + g, 1.0f);
}

// ---------------- final linear: out[g,c] = (pooled[g]/cnt[g]) @ Wlin + blin --
__global__ __launch_bounds__(64) void final_linear(
    const float* __restrict__ pooled, const float* __restrict__ cnt,
    const float* __restrict__ Wlin, const float* __restrict__ blin,
    float* __restrict__ out, int G)
{
  int g = blockIdx.x;
  int c = threadIdx.x;
  if (c >= 20) return;
  float inv = 1.0f / fmaxf(cnt[g], 1.0f);
  float acc = 0.f;
#pragma unroll 4
  for (int i = 0; i < 128; ++i)
    acc += pooled[g * 128 + i] * Wlin[i * 20 + c];
  out[g * 20 + c] = acc * inv + blin[c];
}

// =============================================================================
extern "C" void kernel_launch(void* const* d_in, const int* in_sizes, int n_in,
                              void* d_out, int out_size, void* d_ws, size_t ws_size,
                              hipStream_t stream)
{
  const int N = N_NODES, E = N_EDGES, G = N_GRAPHS;

  const float* x = (const float*)d_in[0];
  const int* ei = (const int*)d_in[1];
  const int* batch = (const int*)d_in[2];
  const float* Wlin = (const float*)d_in[33];
  const float* blin = (const float*)d_in[34];

  char* ws = (char*)d_ws;
  size_t off = 0;
  auto alloc = [&](size_t bytes) -> void* {
    void* p = ws + off;
    off = (off + bytes + 255) & ~(size_t)255;
    return p;
  };
  unsigned short* WT = (unsigned short*)alloc(12 * 16384 * sizeof(unsigned short));
  float* Q      = (float*)alloc((size_t)N * 128 * 4);
  float* K      = (float*)alloc((size_t)N * 128 * 4);
  float* V      = (float*)alloc((size_t)N * 128 * 4);
  float* H      = (float*)alloc((size_t)N * 128 * 4);
  float* logitw = (float*)alloc((size_t)E * 4);
  float* mbuf   = (float*)alloc((size_t)N * 4);
  float* sbuf   = (float*)alloc((size_t)N * 4);
  float* bnsum  = (float*)alloc(128 * 4);       // bnsq contiguous after
  float* bnsq   = (float*)alloc(128 * 4);
  float* scale  = (float*)alloc(128 * 4);
  float* shift  = (float*)alloc(128 * 4);
  float* pooled = (float*)alloc((size_t)G * 128 * 4);  // cnt contiguous after
  float* cnt    = (float*)alloc((size_t)G * 4);
  unsigned short* Xb = (unsigned short*)alloc((size_t)N * 128 * 2);

  WPtrs wp;
  for (int L = 0; L < 3; ++L) {
    wp.w[L * 4 + 0] = (const float*)d_in[3 + L * 10 + 0];  // Wq
    wp.w[L * 4 + 1] = (const float*)d_in[3 + L * 10 + 2];  // Wk
    wp.w[L * 4 + 2] = (const float*)d_in[3 + L * 10 + 4];  // Wv
    wp.w[L * 4 + 3] = (const float*)d_in[3 + L * 10 + 6];  // Ws
  }
  repack_kernel<<<dim3(64, 12), 256, 0, stream>>>(wp, WT);
  f32_to_bf16<<<(N * 128 / 4 + 255) / 256, 256, 0, stream>>>(x, Xb, N * 128 / 4);

  for (int L = 0; L < 3; ++L) {
    GemmOut go;
    go.Y[0] = Q; go.Y[1] = K; go.Y[2] = V; go.Y[3] = H;
    go.bias[0] = (const float*)d_in[3 + L * 10 + 1];
    go.bias[1] = (const float*)d_in[3 + L * 10 + 3];
    go.bias[2] = (const float*)d_in[3 + L * 10 + 5];
    go.bias[3] = (const float*)d_in[3 + L * 10 + 7];
    gemm_proj<<<dim3((N + 63) / 64, 4), 256, 0, stream>>>(Xb, WT + L * 4 * 16384, go, N);

    hipMemsetAsync(sbuf, 0, (size_t)N * 4, stream);
    hipMemsetAsync(mbuf, 0xFF, (size_t)N * 4, stream);   // -NaN sentinel for int-trick max

    edge_logits<<<E / 8, 256, 0, stream>>>(ei, Q, K, logitw, mbuf, E);
    edge_expw<<<(E + 255) / 256, 256, 0, stream>>>(ei, logitw, mbuf, sbuf, E);
    edge_scatter<<<E / 8, 256, 0, stream>>>(ei, logitw, sbuf, V, H, E);

    hipMemsetAsync(bnsum, 0, 2 * 128 * 4, stream);       // bnsum + bnsq
    bn_stats<<<128, 256, 0, stream>>>(H, bnsum, bnsq, N);
    bn_finalize<<<1, 128, 0, stream>>>(bnsum, bnsq,
        (const float*)d_in[3 + L * 10 + 8],
        (const float*)d_in[3 + L * 10 + 9],
        scale, shift, N);

    if (L < 2) {
      bn_apply_relu<<<(N * 128 / 4 + 255) / 256, 256, 0, stream>>>(H, scale, shift, Xb, N * 128);
    } else {
      hipMemsetAsync(pooled, 0, ((size_t)G * 128 + G) * 4, stream);  // pooled + cnt
      pool_kernel<<<N / 8, 256, 0, stream>>>(H, scale, shift, batch, pooled, cnt, N);
    }
  }

  final_linear<<<G, 64, 0, stream>>>(pooled, cnt, Wlin, blin, (float*)d_out, G);
}

// Round 3
// 1017.907 us; speedup vs baseline: 2.9010x; 2.9010x over previous
//
#include <hip/hip_runtime.h>

#define N_NODES 50000
#define N_EDGES 400000
#define DH 128
#define N_GRAPHS 256

typedef __bf16 bf16x8 __attribute__((ext_vector_type(8)));
typedef float f32x4 __attribute__((ext_vector_type(4)));

#define DEV __device__ __forceinline__

DEV unsigned short f2bf(float f) {
  union { float f; unsigned int i; } v; v.f = f;
  unsigned int x = v.i;
  unsigned int r = (x + 0x7fffu + ((x >> 16) & 1u)) >> 16;
  return (unsigned short)r;
}

// ---------------- weight repack: WT[o*128+i] = bf16(W[i*128+o]) --------------
struct WPtrs { const float* w[12]; };

__global__ void repack_kernel(WPtrs wp, unsigned short* __restrict__ WT) {
  int mat = blockIdx.y;
  int idx = blockIdx.x * 256 + threadIdx.x;   // 0..16383
  int i = idx >> 7, o = idx & 127;
  WT[mat * 16384 + o * 128 + i] = f2bf(wp.w[mat][i * 128 + o]);
}

// ---------------- fp32 -> bf16 convert (layer-0 x) ---------------------------
__global__ void f32_to_bf16(const float* __restrict__ in, unsigned short* __restrict__ out,
                            int total4) {
  int i = blockIdx.x * 256 + threadIdx.x;
  if (i >= total4) return;
  float4 v = *reinterpret_cast<const float4*>(in + i * 4);
  ushort4 o;
  o.x = f2bf(v.x); o.y = f2bf(v.y); o.z = f2bf(v.z); o.w = f2bf(v.w);
  *reinterpret_cast<ushort4*>(out + i * 4) = o;
}

// ---------------- CSR build --------------------------------------------------
__global__ void deg_count(const int* __restrict__ ei, int* __restrict__ deg, int E) {
  int e = blockIdx.x * 256 + threadIdx.x;
  if (e < E) atomicAdd(&deg[ei[E + e]], 1);
}

// single-block exclusive scan: rowptr[0..N], cursor[i]=rowptr[i]
__global__ __launch_bounds__(256) void scan_kernel(const int* __restrict__ deg,
                                                   int* __restrict__ rowptr,
                                                   int* __restrict__ cursor, int N) {
  __shared__ int sums[256];
  int t = threadIdx.x;
  int chunk = (N + 255) / 256;
  int lo = t * chunk, hi = min(lo + chunk, N);
  int s = 0;
  for (int i = lo; i < hi; ++i) s += deg[i];
  sums[t] = s;
  __syncthreads();
  for (int off = 1; off < 256; off <<= 1) {
    int other = (t >= off) ? sums[t - off] : 0;
    __syncthreads();
    sums[t] += other;
    __syncthreads();
  }
  int run = sums[t] - s;                // exclusive prefix
  for (int i = lo; i < hi; ++i) { rowptr[i] = run; cursor[i] = run; run += deg[i]; }
  if (hi == N && lo < N) rowptr[N] = run;
  if (t == 0 && N == 0) rowptr[0] = 0;
}

__global__ void csr_scatter(const int* __restrict__ ei, int* __restrict__ cursor,
                            int* __restrict__ adj, int E) {
  int e = blockIdx.x * 256 + threadIdx.x;
  if (e < E) {
    int dst = ei[E + e];
    int pos = atomicAdd(&cursor[dst], 1);
    adj[pos] = ei[e];                   // store src id directly
  }
}

// ---------------- fused projection GEMM: Y = X @ W + b  ----------------------
struct GemmOut { float* Y[4]; const float* bias[4]; };

#define LDP 136   // padded LDS row stride (bf16 elems)

__global__ __launch_bounds__(256) void gemm_proj(
    const unsigned short* __restrict__ X,
    const unsigned short* __restrict__ WT4,
    GemmOut go, int N)
{
  __shared__ __align__(16) unsigned short xs[64 * LDP];
  __shared__ __align__(16) unsigned short wsh[128 * LDP];

  const int proj = blockIdx.y;
  const unsigned short* WT = WT4 + proj * 16384;
  float* __restrict__ Y = go.Y[proj];
  const float* __restrict__ bias = go.bias[proj];

  const int t = threadIdx.x;
  const int rowBase = blockIdx.x * 64;

#pragma unroll
  for (int j = 0; j < 8; ++j) {
    int v = t + 256 * j;
    int o = v >> 4;
    int ig = (v & 15) * 8;
    uint4 val = *reinterpret_cast<const uint4*>(WT + o * 128 + ig);
    *reinterpret_cast<uint4*>(&wsh[o * LDP + ig]) = val;
  }
#pragma unroll
  for (int j = 0; j < 4; ++j) {
    int v = t + 256 * j;
    int r = v >> 4;
    int ig = (v & 15) * 8;
    int grow = rowBase + r;
    uint4 val = make_uint4(0u, 0u, 0u, 0u);
    if (grow < N) val = *reinterpret_cast<const uint4*>(X + grow * 128 + ig);
    *reinterpret_cast<uint4*>(&xs[r * LDP + ig]) = val;
  }
  __syncthreads();

  const int wave = t >> 6;
  const int lane = t & 63;
  const int ln16 = lane & 15;
  const int quad = lane >> 4;
  const int r0 = wave * 16;

  f32x4 acc[8] = {};

#pragma unroll
  for (int kk = 0; kk < 4; ++kk) {
    bf16x8 a = *reinterpret_cast<const bf16x8*>(&xs[(r0 + ln16) * LDP + kk * 32 + quad * 8]);
#pragma unroll
    for (int ct = 0; ct < 8; ++ct) {
      bf16x8 b = *reinterpret_cast<const bf16x8*>(&wsh[(ct * 16 + ln16) * LDP + kk * 32 + quad * 8]);
      acc[ct] = __builtin_amdgcn_mfma_f32_16x16x32_bf16(a, b, acc[ct], 0, 0, 0);
    }
  }

#pragma unroll
  for (int ct = 0; ct < 8; ++ct) {
    int col = ct * 16 + ln16;
    float bv = bias[col];
#pragma unroll
    for (int reg = 0; reg < 4; ++reg) {
      int grow = rowBase + r0 + quad * 4 + reg;
      if (grow < N) Y[grow * 128 + col] = acc[ct][reg] + bv;
    }
  }
}

// ---------------- fused per-node attention (gather, online softmax) ----------
// 32 lanes per dst node; 8 nodes per 256-thread block.
__global__ __launch_bounds__(256) void node_attn(
    const int* __restrict__ rowptr, const int* __restrict__ adj,
    const float* __restrict__ Q, const float* __restrict__ K,
    const float* __restrict__ V, float* __restrict__ H, int N)
{
  int n = blockIdx.x * 8 + (threadIdx.x >> 5);
  int lane = threadIdx.x & 31;
  if (n >= N) return;
  int p0 = rowptr[n], p1 = rowptr[n + 1];

  float4 q = *reinterpret_cast<const float4*>(Q + n * 128 + lane * 4);
  float m = -INFINITY, s = 0.f;
  float4 acc = make_float4(0.f, 0.f, 0.f, 0.f);

  for (int p = p0; p < p1; ++p) {
    int src = adj[p];
    float4 k = *reinterpret_cast<const float4*>(K + src * 128 + lane * 4);
    float d = q.x * k.x + q.y * k.y + q.z * k.z + q.w * k.w;
#pragma unroll
    for (int off = 16; off; off >>= 1) d += __shfl_xor(d, off, 32);
    float logit = d * 0.08838834764831845f;   // 1/sqrt(128)
    float mn = fmaxf(m, logit);
    float sc = __expf(m - mn);
    float w = __expf(logit - mn);
    float4 v = *reinterpret_cast<const float4*>(V + src * 128 + lane * 4);
    acc.x = acc.x * sc + w * v.x;
    acc.y = acc.y * sc + w * v.y;
    acc.z = acc.z * sc + w * v.z;
    acc.w = acc.w * sc + w * v.w;
    s = s * sc + w;
    m = mn;
  }

  float inv = 1.0f / (s + 1e-16f);
  float4 h = *reinterpret_cast<const float4*>(H + n * 128 + lane * 4);
  h.x += acc.x * inv;
  h.y += acc.y * inv;
  h.z += acc.z * inv;
  h.w += acc.w * inv;
  *reinterpret_cast<float4*>(H + n * 128 + lane * 4) = h;
}

// ---------------- batchnorm stats --------------------------------------------
__global__ __launch_bounds__(256) void bn_stats(
    const float* __restrict__ H, float* __restrict__ bnsum,
    float* __restrict__ bnsq, int N)
{
  __shared__ float red[512];
  int t = threadIdx.x;
  int f = t & 127, half = t >> 7;
  float s = 0.f, s2 = 0.f;
  for (int row = blockIdx.x * 2 + half; row < N; row += 256) {
    float v = H[row * 128 + f];
    s += v; s2 += v * v;
  }
  red[t] = s; red[256 + t] = s2;
  __syncthreads();
  if (t < 128) {
    s = red[t] + red[t + 128];
    s2 = red[256 + t] + red[384 + t];
    unsafeAtomicAdd(bnsum + f, s);
    unsafeAtomicAdd(bnsq + f, s2);
  }
}

__global__ void bn_finalize(const float* __restrict__ bnsum, const float* __restrict__ bnsq,
                            const float* __restrict__ gamma,
                            const float* __restrict__ beta,
                            float* __restrict__ scale, float* __restrict__ shift, int N)
{
  int f = threadIdx.x;   // 128 threads
  float mean = bnsum[f] / (float)N;
  float var = bnsq[f] / (float)N - mean * mean;
  var = fmaxf(var, 0.f);
  float sc = gamma[f] * rsqrtf(var + 1e-5f);
  scale[f] = sc;
  shift[f] = beta[f] - mean * sc;
}

// ---------------- apply BN + relu, write bf16 for next layer -----------------
__global__ void bn_apply_relu(const float* __restrict__ H, const float* __restrict__ scale,
                              const float* __restrict__ shift, unsigned short* __restrict__ Xb,
                              int total)
{
  int i4 = (blockIdx.x * 256 + threadIdx.x) * 4;
  if (i4 >= total) return;
  int f = i4 & 127;
  float4 h = *reinterpret_cast<const float4*>(H + i4);
  float4 sc = *reinterpret_cast<const float4*>(scale + f);
  float4 sh = *reinterpret_cast<const float4*>(shift + f);
  ushort4 o;
  o.x = f2bf(fmaxf(h.x * sc.x + sh.x, 0.f));
  o.y = f2bf(fmaxf(h.y * sc.y + sh.y, 0.f));
  o.z = f2bf(fmaxf(h.z * sc.z + sh.z, 0.f));
  o.w = f2bf(fmaxf(h.w * sc.w + sh.w, 0.f));
  *reinterpret_cast<ushort4*>(Xb + i4) = o;
}

// ---------------- global mean pool (layer 3, fused BN+relu) ------------------
__global__ __launch_bounds__(256) void pool_kernel(
    const float* __restrict__ H, const float* __restrict__ scale,
    const float* __restrict__ shift, const int* __restrict__ batch,
    float* __restrict__ pooled, float* __restrict__ cnt, int N)
{
  int n = blockIdx.x * 8 + (threadIdx.x >> 5);
  int lane = threadIdx.x & 31;
  if (n >= N) return;
  int g = batch[n];
  int f = lane * 4;
  float4 h = *reinterpret_cast<const float4*>(H + n * 128 + f);
  float4 sc = *reinterpret_cast<const float4*>(scale + f);
  float4 sh = *reinterpret_cast<const float4*>(shift + f);
  float* p = pooled + g * 128 + f;
  unsafeAtomicAdd(p + 0, fmaxf(h.x * sc.x + sh.x, 0.f));
  unsafeAtomicAdd(p + 1, fmaxf(h.y * sc.y + sh.y, 0.f));
  unsafeAtomicAdd(p + 2, fmaxf(h.z * sc.z + sh.z, 0.f));
  unsafeAtomicAdd(p + 3, fmaxf(h.w * sc.w + sh.w, 0.f));
  if (lane == 0) unsafeAtomicAdd(cnt + g, 1.0f);
}

// ---------------- final linear -----------------------------------------------
__global__ __launch_bounds__(64) void final_linear(
    const float* __restrict__ pooled, const float* __restrict__ cnt,
    const float* __restrict__ Wlin, const float* __restrict__ blin,
    float* __restrict__ out, int G)
{
  int g = blockIdx.x;
  int c = threadIdx.x;
  if (c >= 20) return;
  float inv = 1.0f / fmaxf(cnt[g], 1.0f);
  float acc = 0.f;
#pragma unroll 4
  for (int i = 0; i < 128; ++i)
    acc += pooled[g * 128 + i] * Wlin[i * 20 + c];
  out[g * 20 + c] = acc * inv + blin[c];
}

// =============================================================================
extern "C" void kernel_launch(void* const* d_in, const int* in_sizes, int n_in,
                              void* d_out, int out_size, void* d_ws, size_t ws_size,
                              hipStream_t stream)
{
  const int N = N_NODES, E = N_EDGES, G = N_GRAPHS;

  const float* x = (const float*)d_in[0];
  const int* ei = (const int*)d_in[1];
  const int* batch = (const int*)d_in[2];
  const float* Wlin = (const float*)d_in[33];
  const float* blin = (const float*)d_in[34];

  char* ws = (char*)d_ws;
  size_t off = 0;
  auto alloc = [&](size_t bytes) -> void* {
    void* p = ws + off;
    off = (off + bytes + 255) & ~(size_t)255;
    return p;
  };
  unsigned short* WT = (unsigned short*)alloc(12 * 16384 * sizeof(unsigned short));
  float* Q      = (float*)alloc((size_t)N * 128 * 4);
  float* K      = (float*)alloc((size_t)N * 128 * 4);
  float* V      = (float*)alloc((size_t)N * 128 * 4);
  float* H      = (float*)alloc((size_t)N * 128 * 4);
  int* deg      = (int*)alloc((size_t)N * 4);
  int* rowptr   = (int*)alloc((size_t)(N + 1) * 4);
  int* cursor   = (int*)alloc((size_t)N * 4);
  int* adj      = (int*)alloc((size_t)E * 4);
  float* bnsum  = (float*)alloc(128 * 4);       // bnsq contiguous after
  float* bnsq   = (float*)alloc(128 * 4);
  float* scale  = (float*)alloc(128 * 4);
  float* shift  = (float*)alloc(128 * 4);
  float* pooled = (float*)alloc((size_t)G * 128 * 4);  // cnt contiguous after
  float* cnt    = (float*)alloc((size_t)G * 4);
  unsigned short* Xb = (unsigned short*)alloc((size_t)N * 128 * 2);

  // ---- one-time per launch: weight repack, x->bf16, CSR build ----
  WPtrs wp;
  for (int L = 0; L < 3; ++L) {
    wp.w[L * 4 + 0] = (const float*)d_in[3 + L * 10 + 0];  // Wq
    wp.w[L * 4 + 1] = (const float*)d_in[3 + L * 10 + 2];  // Wk
    wp.w[L * 4 + 2] = (const float*)d_in[3 + L * 10 + 4];  // Wv
    wp.w[L * 4 + 3] = (const float*)d_in[3 + L * 10 + 6];  // Ws
  }
  repack_kernel<<<dim3(64, 12), 256, 0, stream>>>(wp, WT);
  f32_to_bf16<<<(N * 128 / 4 + 255) / 256, 256, 0, stream>>>(x, Xb, N * 128 / 4);

  hipMemsetAsync(deg, 0, (size_t)N * 4, stream);
  deg_count<<<(E + 255) / 256, 256, 0, stream>>>(ei, deg, E);
  scan_kernel<<<1, 256, 0, stream>>>(deg, rowptr, cursor, N);
  csr_scatter<<<(E + 255) / 256, 256, 0, stream>>>(ei, cursor, adj, E);

  for (int L = 0; L < 3; ++L) {
    GemmOut go;
    go.Y[0] = Q; go.Y[1] = K; go.Y[2] = V; go.Y[3] = H;
    go.bias[0] = (const float*)d_in[3 + L * 10 + 1];
    go.bias[1] = (const float*)d_in[3 + L * 10 + 3];
    go.bias[2] = (const float*)d_in[3 + L * 10 + 5];
    go.bias[3] = (const float*)d_in[3 + L * 10 + 7];
    gemm_proj<<<dim3((N + 63) / 64, 4), 256, 0, stream>>>(Xb, WT + L * 4 * 16384, go, N);

    node_attn<<<(N + 7) / 8, 256, 0, stream>>>(rowptr, adj, Q, K, V, H, N);

    hipMemsetAsync(bnsum, 0, 2 * 128 * 4, stream);       // bnsum + bnsq
    bn_stats<<<128, 256, 0, stream>>>(H, bnsum, bnsq, N);
    bn_finalize<<<1, 128, 0, stream>>>(bnsum, bnsq,
        (const float*)d_in[3 + L * 10 + 8],
        (const float*)d_in[3 + L * 10 + 9],
        scale, shift, N);

    if (L < 2) {
      bn_apply_relu<<<(N * 128 / 4 + 255) / 256, 256, 0, stream>>>(H, scale, shift, Xb, N * 128);
    } else {
      hipMemsetAsync(pooled, 0, ((size_t)G * 128 + G) * 4, stream);  // pooled + cnt
      pool_kernel<<<N / 8, 256, 0, stream>>>(H, scale, shift, batch, pooled, cnt, N);
    }
  }

  final_linear<<<G, 64, 0, stream>>>(pooled, cnt, Wlin, blin, (float*)d_out, G);
}

// Round 4
// 835.066 us; speedup vs baseline: 3.5362x; 1.2190x over previous
//
#include <hip/hip_runtime.h>

#define N_NODES 50000
#define N_EDGES 400000
#define DH 128
#define N_GRAPHS 256

typedef __bf16 bf16x8 __attribute__((ext_vector_type(8)));
typedef float f32x4 __attribute__((ext_vector_type(4)));

#define DEV __device__ __forceinline__

DEV unsigned short f2bf(float f) {
  union { float f; unsigned int i; } v; v.f = f;
  unsigned int x = v.i;
  unsigned int r = (x + 0x7fffu + ((x >> 16) & 1u)) >> 16;
  return (unsigned short)r;
}

// ---------------- weight repack: WT[o*128+i] = bf16(W[i*128+o]) --------------
struct WPtrs { const float* w[12]; };

__global__ void repack_kernel(WPtrs wp, unsigned short* __restrict__ WT) {
  int mat = blockIdx.y;
  int idx = blockIdx.x * 256 + threadIdx.x;   // 0..16383
  int i = idx >> 7, o = idx & 127;
  WT[mat * 16384 + o * 128 + i] = f2bf(wp.w[mat][i * 128 + o]);
}

// ---------------- fp32 -> bf16 convert (layer-0 x) ---------------------------
__global__ void f32_to_bf16(const float* __restrict__ in, unsigned short* __restrict__ out,
                            int total4) {
  int i = blockIdx.x * 256 + threadIdx.x;
  if (i >= total4) return;
  float4 v = *reinterpret_cast<const float4*>(in + i * 4);
  ushort4 o;
  o.x = f2bf(v.x); o.y = f2bf(v.y); o.z = f2bf(v.z); o.w = f2bf(v.w);
  *reinterpret_cast<ushort4*>(out + i * 4) = o;
}

// ---------------- CSR build --------------------------------------------------
__global__ void deg_count(const int* __restrict__ ei, int* __restrict__ deg, int E) {
  int e = blockIdx.x * 256 + threadIdx.x;
  if (e < E) atomicAdd(&deg[ei[E + e]], 1);
}

__global__ __launch_bounds__(256) void scan_kernel(const int* __restrict__ deg,
                                                   int* __restrict__ rowptr,
                                                   int* __restrict__ cursor, int N) {
  __shared__ int sums[256];
  int t = threadIdx.x;
  int chunk = (N + 255) / 256;
  int lo = t * chunk, hi = min(lo + chunk, N);
  int s = 0;
  for (int i = lo; i < hi; ++i) s += deg[i];
  sums[t] = s;
  __syncthreads();
  for (int off = 1; off < 256; off <<= 1) {
    int other = (t >= off) ? sums[t - off] : 0;
    __syncthreads();
    sums[t] += other;
    __syncthreads();
  }
  int run = sums[t] - s;                // exclusive prefix
  for (int i = lo; i < hi; ++i) { rowptr[i] = run; cursor[i] = run; run += deg[i]; }
  if (hi == N && lo < N) rowptr[N] = run;
}

__global__ void csr_scatter(const int* __restrict__ ei, int* __restrict__ cursor,
                            int* __restrict__ adj, int E) {
  int e = blockIdx.x * 256 + threadIdx.x;
  if (e < E) {
    int dst = ei[E + e];
    int pos = atomicAdd(&cursor[dst], 1);
    adj[pos] = ei[e];                   // store src id directly
  }
}

// ---------------- fused projection GEMM: Y = X @ W + b  ----------------------
struct GemmOut { float* Y[4]; const float* bias[4]; };

#define LDP 136   // padded LDS row stride (bf16 elems)

__global__ __launch_bounds__(256) void gemm_proj(
    const unsigned short* __restrict__ X,
    const unsigned short* __restrict__ WT4,
    GemmOut go, int N)
{
  __shared__ __align__(16) unsigned short xs[64 * LDP];
  __shared__ __align__(16) unsigned short wsh[128 * LDP];

  const int proj = blockIdx.y;
  const unsigned short* WT = WT4 + proj * 16384;
  float* __restrict__ Y = go.Y[proj];
  const float* __restrict__ bias = go.bias[proj];

  const int t = threadIdx.x;
  const int rowBase = blockIdx.x * 64;

#pragma unroll
  for (int j = 0; j < 8; ++j) {
    int v = t + 256 * j;
    int o = v >> 4;
    int ig = (v & 15) * 8;
    uint4 val = *reinterpret_cast<const uint4*>(WT + o * 128 + ig);
    *reinterpret_cast<uint4*>(&wsh[o * LDP + ig]) = val;
  }
#pragma unroll
  for (int j = 0; j < 4; ++j) {
    int v = t + 256 * j;
    int r = v >> 4;
    int ig = (v & 15) * 8;
    int grow = rowBase + r;
    uint4 val = make_uint4(0u, 0u, 0u, 0u);
    if (grow < N) val = *reinterpret_cast<const uint4*>(X + grow * 128 + ig);
    *reinterpret_cast<uint4*>(&xs[r * LDP + ig]) = val;
  }
  __syncthreads();

  const int wave = t >> 6;
  const int lane = t & 63;
  const int ln16 = lane & 15;
  const int quad = lane >> 4;
  const int r0 = wave * 16;

  f32x4 acc[8] = {};

#pragma unroll
  for (int kk = 0; kk < 4; ++kk) {
    bf16x8 a = *reinterpret_cast<const bf16x8*>(&xs[(r0 + ln16) * LDP + kk * 32 + quad * 8]);
#pragma unroll
    for (int ct = 0; ct < 8; ++ct) {
      bf16x8 b = *reinterpret_cast<const bf16x8*>(&wsh[(ct * 16 + ln16) * LDP + kk * 32 + quad * 8]);
      acc[ct] = __builtin_amdgcn_mfma_f32_16x16x32_bf16(a, b, acc[ct], 0, 0, 0);
    }
  }

#pragma unroll
  for (int ct = 0; ct < 8; ++ct) {
    int col = ct * 16 + ln16;
    float bv = bias[col];
#pragma unroll
    for (int reg = 0; reg < 4; ++reg) {
      int grow = rowBase + r0 + quad * 4 + reg;
      if (grow < N) Y[grow * 128 + col] = acc[ct][reg] + bv;
    }
  }
}

// ---------------- fused per-node attention (gather, online softmax) ----------
__global__ __launch_bounds__(256) void node_attn(
    const int* __restrict__ rowptr, const int* __restrict__ adj,
    const float* __restrict__ Q, const float* __restrict__ K,
    const float* __restrict__ V, float* __restrict__ H, int N)
{
  int n = blockIdx.x * 8 + (threadIdx.x >> 5);
  int lane = threadIdx.x & 31;
  if (n >= N) return;
  int p0 = rowptr[n], p1 = rowptr[n + 1];

  float4 q = *reinterpret_cast<const float4*>(Q + n * 128 + lane * 4);
  float m = -INFINITY, s = 0.f;
  float4 acc = make_float4(0.f, 0.f, 0.f, 0.f);

  for (int p = p0; p < p1; ++p) {
    int src = adj[p];
    float4 k = *reinterpret_cast<const float4*>(K + src * 128 + lane * 4);
    float d = q.x * k.x + q.y * k.y + q.z * k.z + q.w * k.w;
#pragma unroll
    for (int off = 16; off; off >>= 1) d += __shfl_xor(d, off, 32);
    float logit = d * 0.08838834764831845f;   // 1/sqrt(128)
    float mn = fmaxf(m, logit);
    float sc = __expf(m - mn);
    float w = __expf(logit - mn);
    float4 v = *reinterpret_cast<const float4*>(V + src * 128 + lane * 4);
    acc.x = acc.x * sc + w * v.x;
    acc.y = acc.y * sc + w * v.y;
    acc.z = acc.z * sc + w * v.z;
    acc.w = acc.w * sc + w * v.w;
    s = s * sc + w;
    m = mn;
  }

  float inv = 1.0f / (s + 1e-16f);
  float4 h = *reinterpret_cast<const float4*>(H + n * 128 + lane * 4);
  h.x += acc.x * inv;
  h.y += acc.y * inv;
  h.z += acc.z * inv;
  h.w += acc.w * inv;
  *reinterpret_cast<float4*>(H + n * 128 + lane * 4) = h;
}

// ---------------- batchnorm stats --------------------------------------------
__global__ __launch_bounds__(256) void bn_stats(
    const float* __restrict__ H, float* __restrict__ bnsum,
    float* __restrict__ bnsq, int N)
{
  __shared__ float red[512];
  int t = threadIdx.x;
  int f = t & 127, half = t >> 7;
  float s = 0.f, s2 = 0.f;
  for (int row = blockIdx.x * 2 + half; row < N; row += 256) {
    float v = H[row * 128 + f];
    s += v; s2 += v * v;
  }
  red[t] = s; red[256 + t] = s2;
  __syncthreads();
  if (t < 128) {
    s = red[t] + red[t + 128];
    s2 = red[256 + t] + red[384 + t];
    unsafeAtomicAdd(bnsum + f, s);
    unsafeAtomicAdd(bnsq + f, s2);
  }
}

__global__ void bn_finalize(const float* __restrict__ bnsum, const float* __restrict__ bnsq,
                            const float* __restrict__ gamma,
                            const float* __restrict__ beta,
                            float* __restrict__ scale, float* __restrict__ shift, int N)
{
  int f = threadIdx.x;   // 128 threads
  float mean = bnsum[f] / (float)N;
  float var = bnsq[f] / (float)N - mean * mean;
  var = fmaxf(var, 0.f);
  float sc = gamma[f] * rsqrtf(var + 1e-5f);
  scale[f] = sc;
  shift[f] = beta[f] - mean * sc;
}

// ---------------- apply BN + relu, write bf16 for next layer -----------------
__global__ void bn_apply_relu(const float* __restrict__ H, const float* __restrict__ scale,
                              const float* __restrict__ shift, unsigned short* __restrict__ Xb,
                              int total)
{
  int i4 = (blockIdx.x * 256 + threadIdx.x) * 4;
  if (i4 >= total) return;
  int f = i4 & 127;
  float4 h = *reinterpret_cast<const float4*>(H + i4);
  float4 sc = *reinterpret_cast<const float4*>(scale + f);
  float4 sh = *reinterpret_cast<const float4*>(shift + f);
  ushort4 o;
  o.x = f2bf(fmaxf(h.x * sc.x + sh.x, 0.f));
  o.y = f2bf(fmaxf(h.y * sc.y + sh.y, 0.f));
  o.z = f2bf(fmaxf(h.z * sc.z + sh.z, 0.f));
  o.w = f2bf(fmaxf(h.w * sc.w + sh.w, 0.f));
  *reinterpret_cast<ushort4*>(Xb + i4) = o;
}

// ---------------- per-graph pool (BN+ReLU fused) + linear head ---------------
// one block per graph; batch is sorted so each graph is a contiguous node range
__global__ __launch_bounds__(256) void pool_linear(
    const float* __restrict__ H, const float* __restrict__ scale,
    const float* __restrict__ shift, const int* __restrict__ batch,
    const float* __restrict__ Wlin, const float* __restrict__ blin,
    float* __restrict__ out, int N)
{
  __shared__ float red[256];
  __shared__ float pool[128];
  int g = blockIdx.x;
  int t = threadIdx.x;

  // lower_bound(batch, g) and lower_bound(batch, g+1), redundantly per thread
  int lo = 0, hi = N;
  while (lo < hi) { int mid = (lo + hi) >> 1; if (batch[mid] < g) lo = mid + 1; else hi = mid; }
  int start = lo;
  hi = N;
  while (lo < hi) { int mid = (lo + hi) >> 1; if (batch[mid] < g + 1) lo = mid + 1; else hi = mid; }
  int end = lo;
  int cnt = end - start;

  int f = t & 127, half = t >> 7;
  float sc = scale[f], sh = shift[f];
  float s = 0.f;
  for (int row = start + half; row < end; row += 2)
    s += fmaxf(H[row * 128 + f] * sc + sh, 0.f);
  red[t] = s;
  __syncthreads();
  if (t < 128)
    pool[t] = (red[t] + red[t + 128]) / fmaxf((float)cnt, 1.f);
  __syncthreads();

  if (t < 20) {
    float acc = 0.f;
#pragma unroll 4
    for (int i = 0; i < 128; ++i)
      acc += pool[i] * Wlin[i * 20 + t];
    out[g * 20 + t] = acc + blin[t];
  }
}

// =============================================================================
extern "C" void kernel_launch(void* const* d_in, const int* in_sizes, int n_in,
                              void* d_out, int out_size, void* d_ws, size_t ws_size,
                              hipStream_t stream)
{
  const int N = N_NODES, E = N_EDGES, G = N_GRAPHS;

  const float* x = (const float*)d_in[0];
  const int* ei = (const int*)d_in[1];
  const int* batch = (const int*)d_in[2];
  const float* Wlin = (const float*)d_in[33];
  const float* blin = (const float*)d_in[34];

  char* ws = (char*)d_ws;
  size_t off = 0;
  auto alloc = [&](size_t bytes) -> void* {
    void* p = ws + off;
    off = (off + bytes + 255) & ~(size_t)255;
    return p;
  };
  unsigned short* WT = (unsigned short*)alloc(12 * 16384 * sizeof(unsigned short));
  float* Q      = (float*)alloc((size_t)N * 128 * 4);
  float* K      = (float*)alloc((size_t)N * 128 * 4);
  float* V      = (float*)alloc((size_t)N * 128 * 4);
  float* H      = (float*)alloc((size_t)N * 128 * 4);
  int* deg      = (int*)alloc((size_t)N * 4);
  int* rowptr   = (int*)alloc((size_t)(N + 1) * 4);
  int* cursor   = (int*)alloc((size_t)N * 4);
  int* adj      = (int*)alloc((size_t)E * 4);
  float* bnsum  = (float*)alloc(128 * 4);       // bnsq contiguous after
  float* bnsq   = (float*)alloc(128 * 4);
  float* scale  = (float*)alloc(128 * 4);
  float* shift  = (float*)alloc(128 * 4);
  unsigned short* Xb = (unsigned short*)alloc((size_t)N * 128 * 2);

  // ---- one-time per launch: weight repack, x->bf16, CSR build ----
  WPtrs wp;
  for (int L = 0; L < 3; ++L) {
    wp.w[L * 4 + 0] = (const float*)d_in[3 + L * 10 + 0];  // Wq
    wp.w[L * 4 + 1] = (const float*)d_in[3 + L * 10 + 2];  // Wk
    wp.w[L * 4 + 2] = (const float*)d_in[3 + L * 10 + 4];  // Wv
    wp.w[L * 4 + 3] = (const float*)d_in[3 + L * 10 + 6];  // Ws
  }
  repack_kernel<<<dim3(64, 12), 256, 0, stream>>>(wp, WT);
  f32_to_bf16<<<(N * 128 / 4 + 255) / 256, 256, 0, stream>>>(x, Xb, N * 128 / 4);

  hipMemsetAsync(deg, 0, (size_t)N * 4, stream);
  deg_count<<<(E + 255) / 256, 256, 0, stream>>>(ei, deg, E);
  scan_kernel<<<1, 256, 0, stream>>>(deg, rowptr, cursor, N);
  csr_scatter<<<(E + 255) / 256, 256, 0, stream>>>(ei, cursor, adj, E);

  for (int L = 0; L < 3; ++L) {
    GemmOut go;
    go.Y[0] = Q; go.Y[1] = K; go.Y[2] = V; go.Y[3] = H;
    go.bias[0] = (const float*)d_in[3 + L * 10 + 1];
    go.bias[1] = (const float*)d_in[3 + L * 10 + 3];
    go.bias[2] = (const float*)d_in[3 + L * 10 + 5];
    go.bias[3] = (const float*)d_in[3 + L * 10 + 7];
    gemm_proj<<<dim3((N + 63) / 64, 4), 256, 0, stream>>>(Xb, WT + L * 4 * 16384, go, N);

    node_attn<<<(N + 7) / 8, 256, 0, stream>>>(rowptr, adj, Q, K, V, H, N);

    hipMemsetAsync(bnsum, 0, 2 * 128 * 4, stream);       // bnsum + bnsq
    bn_stats<<<128, 256, 0, stream>>>(H, bnsum, bnsq, N);
    bn_finalize<<<1, 128, 0, stream>>>(bnsum, bnsq,
        (const float*)d_in[3 + L * 10 + 8],
        (const float*)d_in[3 + L * 10 + 9],
        scale, shift, N);

    if (L < 2) {
      bn_apply_relu<<<(N * 128 / 4 + 255) / 256, 256, 0, stream>>>(H, scale, shift, Xb, N * 128);
    } else {
      pool_linear<<<G, 256, 0, stream>>>(H, scale, shift, batch, Wlin, blin,
                                         (float*)d_out, N);
    }
  }
}

// Round 5
// 717.394 us; speedup vs baseline: 4.1163x; 1.1640x over previous
//
#include <hip/hip_runtime.h>

#define N_NODES 50000
#define N_EDGES 400000
#define DH 128
#define N_GRAPHS 256

#define SCAN_CHUNK 512
#define N_CHUNKS ((N_NODES + SCAN_CHUNK - 1) / SCAN_CHUNK)   // 98

typedef __bf16 bf16x8 __attribute__((ext_vector_type(8)));
typedef float f32x4 __attribute__((ext_vector_type(4)));

#define DEV __device__ __forceinline__

DEV unsigned short f2bf(float f) {
  union { float f; unsigned int i; } v; v.f = f;
  unsigned int x = v.i;
  unsigned int r = (x + 0x7fffu + ((x >> 16) & 1u)) >> 16;
  return (unsigned short)r;
}

// ---------------- weight repack: WT[o*128+i] = bf16(W[i*128+o]) --------------
struct WPtrs { const float* w[12]; };

__global__ void repack_kernel(WPtrs wp, unsigned short* __restrict__ WT) {
  int mat = blockIdx.y;
  int idx = blockIdx.x * 256 + threadIdx.x;   // 0..16383
  int i = idx >> 7, o = idx & 127;
  WT[mat * 16384 + o * 128 + i] = f2bf(wp.w[mat][i * 128 + o]);
}

// ---------------- fp32 -> bf16 convert (layer-0 x) ---------------------------
__global__ void f32_to_bf16(const float* __restrict__ in, unsigned short* __restrict__ out,
                            int total4) {
  int i = blockIdx.x * 256 + threadIdx.x;
  if (i >= total4) return;
  float4 v = *reinterpret_cast<const float4*>(in + i * 4);
  ushort4 o;
  o.x = f2bf(v.x); o.y = f2bf(v.y); o.z = f2bf(v.z); o.w = f2bf(v.w);
  *reinterpret_cast<ushort4*>(out + i * 4) = o;
}

// ---------------- CSR build --------------------------------------------------
__global__ void deg_count(const int* __restrict__ ei, int* __restrict__ deg, int E) {
  int e = blockIdx.x * 256 + threadIdx.x;
  if (e < E) atomicAdd(&deg[ei[E + e]], 1);
}

// pass 1: per-chunk sums (98 blocks x 256 thr, int2 loads)
__global__ __launch_bounds__(256) void scan_sum(const int* __restrict__ deg,
                                                int* __restrict__ partials, int N) {
  __shared__ int red[256];
  int b = blockIdx.x, t = threadIdx.x;
  int base = b * SCAN_CHUNK + t * 2;
  int s = 0;
  if (base + 1 < N) { int2 v = *reinterpret_cast<const int2*>(deg + base); s = v.x + v.y; }
  else if (base < N) s = deg[base];
  red[t] = s;
  __syncthreads();
  for (int off = 128; off; off >>= 1) {
    if (t < off) red[t] += red[t + off];
    __syncthreads();
  }
  if (t == 0) partials[b] = red[0];
}

// pass 2: exclusive scan of 98 partials (one tiny block)
__global__ __launch_bounds__(128) void scan_partials(int* __restrict__ partials) {
  __shared__ int s[128];
  int t = threadIdx.x;
  int v = (t < N_CHUNKS) ? partials[t] : 0;
  s[t] = v;
  __syncthreads();
  for (int off = 1; off < 128; off <<= 1) {
    int o = (t >= off) ? s[t - off] : 0;
    __syncthreads();
    s[t] += o;
    __syncthreads();
  }
  if (t < N_CHUNKS) partials[t] = s[t] - v;   // exclusive
}

// pass 3: apply — block scan within chunk, write rowptr + cursor
__global__ __launch_bounds__(256) void scan_apply(const int* __restrict__ deg,
                                                  const int* __restrict__ partials,
                                                  int* __restrict__ rowptr,
                                                  int* __restrict__ cursor, int N, int E) {
  __shared__ int s[256];
  int b = blockIdx.x, t = threadIdx.x;
  int base = b * SCAN_CHUNK + t * 2;
  int d0 = 0, d1 = 0;
  if (base + 1 < N) { int2 v = *reinterpret_cast<const int2*>(deg + base); d0 = v.x; d1 = v.y; }
  else if (base < N) d0 = deg[base];
  int local = d0 + d1;
  s[t] = local;
  __syncthreads();
  for (int off = 1; off < 256; off <<= 1) {
    int o = (t >= off) ? s[t - off] : 0;
    __syncthreads();
    s[t] += o;
    __syncthreads();
  }
  int offp = partials[b] + s[t] - local;   // exclusive prefix for elem base
  if (base < N)     { rowptr[base] = offp;          cursor[base] = offp; }
  if (base + 1 < N) { rowptr[base + 1] = offp + d0; cursor[base + 1] = offp + d0; }
  if (b == 0 && t == 0) rowptr[N] = E;
}

__global__ void csr_scatter(const int* __restrict__ ei, int* __restrict__ cursor,
                            int* __restrict__ adj, int E) {
  int e = blockIdx.x * 256 + threadIdx.x;
  if (e < E) {
    int dst = ei[E + e];
    int pos = atomicAdd(&cursor[dst], 1);
    adj[pos] = ei[e];                   // store src id directly
  }
}

// ---------------- fused projection GEMM: Y = X @ W + b  ----------------------
struct GemmOut { float* Y[4]; const float* bias[4]; };

#define LDP 136   // padded LDS row stride (bf16 elems)

__global__ __launch_bounds__(256) void gemm_proj(
    const unsigned short* __restrict__ X,
    const unsigned short* __restrict__ WT4,
    GemmOut go, int N)
{
  __shared__ __align__(16) unsigned short xs[64 * LDP];
  __shared__ __align__(16) unsigned short wsh[128 * LDP];

  const int proj = blockIdx.y;
  const unsigned short* WT = WT4 + proj * 16384;
  float* __restrict__ Y = go.Y[proj];
  const float* __restrict__ bias = go.bias[proj];

  const int t = threadIdx.x;
  const int rowBase = blockIdx.x * 64;

#pragma unroll
  for (int j = 0; j < 8; ++j) {
    int v = t + 256 * j;
    int o = v >> 4;
    int ig = (v & 15) * 8;
    uint4 val = *reinterpret_cast<const uint4*>(WT + o * 128 + ig);
    *reinterpret_cast<uint4*>(&wsh[o * LDP + ig]) = val;
  }
#pragma unroll
  for (int j = 0; j < 4; ++j) {
    int v = t + 256 * j;
    int r = v >> 4;
    int ig = (v & 15) * 8;
    int grow = rowBase + r;
    uint4 val = make_uint4(0u, 0u, 0u, 0u);
    if (grow < N) val = *reinterpret_cast<const uint4*>(X + grow * 128 + ig);
    *reinterpret_cast<uint4*>(&xs[r * LDP + ig]) = val;
  }
  __syncthreads();

  const int wave = t >> 6;
  const int lane = t & 63;
  const int ln16 = lane & 15;
  const int quad = lane >> 4;
  const int r0 = wave * 16;

  f32x4 acc[8] = {};

#pragma unroll
  for (int kk = 0; kk < 4; ++kk) {
    bf16x8 a = *reinterpret_cast<const bf16x8*>(&xs[(r0 + ln16) * LDP + kk * 32 + quad * 8]);
#pragma unroll
    for (int ct = 0; ct < 8; ++ct) {
      bf16x8 b = *reinterpret_cast<const bf16x8*>(&wsh[(ct * 16 + ln16) * LDP + kk * 32 + quad * 8]);
      acc[ct] = __builtin_amdgcn_mfma_f32_16x16x32_bf16(a, b, acc[ct], 0, 0, 0);
    }
  }

#pragma unroll
  for (int ct = 0; ct < 8; ++ct) {
    int col = ct * 16 + ln16;
    float bv = bias[col];
#pragma unroll
    for (int reg = 0; reg < 4; ++reg) {
      int grow = rowBase + r0 + quad * 4 + reg;
      if (grow < N) Y[grow * 128 + col] = acc[ct][reg] + bv;
    }
  }
}

// ---------------- fused per-node attention (gather, online softmax) ----------
// 32 lanes per dst node; unrolled 2 edges/iter for MLP + shorter dep chains.
__global__ __launch_bounds__(256) void node_attn(
    const int* __restrict__ rowptr, const int* __restrict__ adj,
    const float* __restrict__ Q, const float* __restrict__ K,
    const float* __restrict__ V, float* __restrict__ H, int N)
{
  int n = blockIdx.x * 8 + (threadIdx.x >> 5);
  int lane = threadIdx.x & 31;
  if (n >= N) return;
  int p0 = rowptr[n], p1 = rowptr[n + 1];

  float4 q = *reinterpret_cast<const float4*>(Q + n * 128 + lane * 4);
  float m = -INFINITY, s = 0.f;
  float4 acc = make_float4(0.f, 0.f, 0.f, 0.f);

  int p = p0;
  for (; p + 1 < p1; p += 2) {
    int s0 = adj[p], s1 = adj[p + 1];
    float4 k0 = *reinterpret_cast<const float4*>(K + s0 * 128 + lane * 4);
    float4 k1 = *reinterpret_cast<const float4*>(K + s1 * 128 + lane * 4);
    float d0 = q.x * k0.x + q.y * k0.y + q.z * k0.z + q.w * k0.w;
    float d1 = q.x * k1.x + q.y * k1.y + q.z * k1.z + q.w * k1.w;
#pragma unroll
    for (int off = 16; off; off >>= 1) {
      d0 += __shfl_xor(d0, off, 32);
      d1 += __shfl_xor(d1, off, 32);
    }
    float l0 = d0 * 0.08838834764831845f;
    float l1 = d1 * 0.08838834764831845f;
    float mn = fmaxf(m, fmaxf(l0, l1));
    float sc = __expf(m - mn);
    float w0 = __expf(l0 - mn);
    float w1 = __expf(l1 - mn);
    float4 v0 = *reinterpret_cast<const float4*>(V + s0 * 128 + lane * 4);
    float4 v1 = *reinterpret_cast<const float4*>(V + s1 * 128 + lane * 4);
    acc.x = acc.x * sc + w0 * v0.x + w1 * v1.x;
    acc.y = acc.y * sc + w0 * v0.y + w1 * v1.y;
    acc.z = acc.z * sc + w0 * v0.z + w1 * v1.z;
    acc.w = acc.w * sc + w0 * v0.w + w1 * v1.w;
    s = s * sc + w0 + w1;
    m = mn;
  }
  if (p < p1) {
    int s0 = adj[p];
    float4 k0 = *reinterpret_cast<const float4*>(K + s0 * 128 + lane * 4);
    float d0 = q.x * k0.x + q.y * k0.y + q.z * k0.z + q.w * k0.w;
#pragma unroll
    for (int off = 16; off; off >>= 1) d0 += __shfl_xor(d0, off, 32);
    float l0 = d0 * 0.08838834764831845f;
    float mn = fmaxf(m, l0);
    float sc = __expf(m - mn);
    float w0 = __expf(l0 - mn);
    float4 v0 = *reinterpret_cast<const float4*>(V + s0 * 128 + lane * 4);
    acc.x = acc.x * sc + w0 * v0.x;
    acc.y = acc.y * sc + w0 * v0.y;
    acc.z = acc.z * sc + w0 * v0.z;
    acc.w = acc.w * sc + w0 * v0.w;
    s = s * sc + w0;
    m = mn;
  }

  float inv = 1.0f / (s + 1e-16f);
  float4 h = *reinterpret_cast<const float4*>(H + n * 128 + lane * 4);
  h.x += acc.x * inv;
  h.y += acc.y * inv;
  h.z += acc.z * inv;
  h.w += acc.w * inv;
  *reinterpret_cast<float4*>(H + n * 128 + lane * 4) = h;
}

// ---------------- batchnorm stats --------------------------------------------
__global__ __launch_bounds__(256) void bn_stats(
    const float* __restrict__ H, float* __restrict__ bnsum,
    float* __restrict__ bnsq, int N)
{
  __shared__ float red[512];
  int t = threadIdx.x;
  int f = t & 127, half = t >> 7;
  float s = 0.f, s2 = 0.f;
  for (int row = blockIdx.x * 2 + half; row < N; row += 256) {
    float v = H[row * 128 + f];
    s += v; s2 += v * v;
  }
  red[t] = s; red[256 + t] = s2;
  __syncthreads();
  if (t < 128) {
    s = red[t] + red[t + 128];
    s2 = red[256 + t] + red[384 + t];
    unsafeAtomicAdd(bnsum + f, s);
    unsafeAtomicAdd(bnsq + f, s2);
  }
}

__global__ void bn_finalize(const float* __restrict__ bnsum, const float* __restrict__ bnsq,
                            const float* __restrict__ gamma,
                            const float* __restrict__ beta,
                            float* __restrict__ scale, float* __restrict__ shift, int N)
{
  int f = threadIdx.x;   // 128 threads
  float mean = bnsum[f] / (float)N;
  float var = bnsq[f] / (float)N - mean * mean;
  var = fmaxf(var, 0.f);
  float sc = gamma[f] * rsqrtf(var + 1e-5f);
  scale[f] = sc;
  shift[f] = beta[f] - mean * sc;
}

// ---------------- apply BN + relu, write bf16 for next layer -----------------
__global__ void bn_apply_relu(const float* __restrict__ H, const float* __restrict__ scale,
                              const float* __restrict__ shift, unsigned short* __restrict__ Xb,
                              int total)
{
  int i4 = (blockIdx.x * 256 + threadIdx.x) * 4;
  if (i4 >= total) return;
  int f = i4 & 127;
  float4 h = *reinterpret_cast<const float4*>(H + i4);
  float4 sc = *reinterpret_cast<const float4*>(scale + f);
  float4 sh = *reinterpret_cast<const float4*>(shift + f);
  ushort4 o;
  o.x = f2bf(fmaxf(h.x * sc.x + sh.x, 0.f));
  o.y = f2bf(fmaxf(h.y * sc.y + sh.y, 0.f));
  o.z = f2bf(fmaxf(h.z * sc.z + sh.z, 0.f));
  o.w = f2bf(fmaxf(h.w * sc.w + sh.w, 0.f));
  *reinterpret_cast<ushort4*>(Xb + i4) = o;
}

// ---------------- per-graph pool (BN+ReLU fused) + linear head ---------------
__global__ __launch_bounds__(256) void pool_linear(
    const float* __restrict__ H, const float* __restrict__ scale,
    const float* __restrict__ shift, const int* __restrict__ batch,
    const float* __restrict__ Wlin, const float* __restrict__ blin,
    float* __restrict__ out, int N)
{
  __shared__ float red[256];
  __shared__ float pool[128];
  int g = blockIdx.x;
  int t = threadIdx.x;

  int lo = 0, hi = N;
  while (lo < hi) { int mid = (lo + hi) >> 1; if (batch[mid] < g) lo = mid + 1; else hi = mid; }
  int start = lo;
  hi = N;
  while (lo < hi) { int mid = (lo + hi) >> 1; if (batch[mid] < g + 1) lo = mid + 1; else hi = mid; }
  int end = lo;
  int cnt = end - start;

  int f = t & 127, half = t >> 7;
  float sc = scale[f], sh = shift[f];
  float s = 0.f;
  for (int row = start + half; row < end; row += 2)
    s += fmaxf(H[row * 128 + f] * sc + sh, 0.f);
  red[t] = s;
  __syncthreads();
  if (t < 128)
    pool[t] = (red[t] + red[t + 128]) / fmaxf((float)cnt, 1.f);
  __syncthreads();

  if (t < 20) {
    float acc = 0.f;
#pragma unroll 4
    for (int i = 0; i < 128; ++i)
      acc += pool[i] * Wlin[i * 20 + t];
    out[g * 20 + t] = acc + blin[t];
  }
}

// =============================================================================
extern "C" void kernel_launch(void* const* d_in, const int* in_sizes, int n_in,
                              void* d_out, int out_size, void* d_ws, size_t ws_size,
                              hipStream_t stream)
{
  const int N = N_NODES, E = N_EDGES, G = N_GRAPHS;

  const float* x = (const float*)d_in[0];
  const int* ei = (const int*)d_in[1];
  const int* batch = (const int*)d_in[2];
  const float* Wlin = (const float*)d_in[33];
  const float* blin = (const float*)d_in[34];

  char* ws = (char*)d_ws;
  size_t off = 0;
  auto alloc = [&](size_t bytes) -> void* {
    void* p = ws + off;
    off = (off + bytes + 255) & ~(size_t)255;
    return p;
  };
  unsigned short* WT = (unsigned short*)alloc(12 * 16384 * sizeof(unsigned short));
  float* Q      = (float*)alloc((size_t)N * 128 * 4);
  float* K      = (float*)alloc((size_t)N * 128 * 4);
  float* V      = (float*)alloc((size_t)N * 128 * 4);
  float* H      = (float*)alloc((size_t)N * 128 * 4);
  int* deg      = (int*)alloc((size_t)N * 4);
  int* rowptr   = (int*)alloc((size_t)(N + 1) * 4);
  int* cursor   = (int*)alloc((size_t)N * 4);
  int* adj      = (int*)alloc((size_t)E * 4);
  int* partials = (int*)alloc((size_t)N_CHUNKS * 4);
  float* bnsum  = (float*)alloc(128 * 4);       // bnsq contiguous after
  float* bnsq   = (float*)alloc(128 * 4);
  float* scale  = (float*)alloc(128 * 4);
  float* shift  = (float*)alloc(128 * 4);
  unsigned short* Xb = (unsigned short*)alloc((size_t)N * 128 * 2);

  // ---- one-time per launch: weight repack, x->bf16, CSR build ----
  WPtrs wp;
  for (int L = 0; L < 3; ++L) {
    wp.w[L * 4 + 0] = (const float*)d_in[3 + L * 10 + 0];  // Wq
    wp.w[L * 4 + 1] = (const float*)d_in[3 + L * 10 + 2];  // Wk
    wp.w[L * 4 + 2] = (const float*)d_in[3 + L * 10 + 4];  // Wv
    wp.w[L * 4 + 3] = (const float*)d_in[3 + L * 10 + 6];  // Ws
  }
  repack_kernel<<<dim3(64, 12), 256, 0, stream>>>(wp, WT);
  f32_to_bf16<<<(N * 128 / 4 + 255) / 256, 256, 0, stream>>>(x, Xb, N * 128 / 4);

  hipMemsetAsync(deg, 0, (size_t)N * 4, stream);
  deg_count<<<(E + 255) / 256, 256, 0, stream>>>(ei, deg, E);
  scan_sum<<<N_CHUNKS, 256, 0, stream>>>(deg, partials, N);
  scan_partials<<<1, 128, 0, stream>>>(partials);
  scan_apply<<<N_CHUNKS, 256, 0, stream>>>(deg, partials, rowptr, cursor, N, E);
  csr_scatter<<<(E + 255) / 256, 256, 0, stream>>>(ei, cursor, adj, E);

  for (int L = 0; L < 3; ++L) {
    GemmOut go;
    go.Y[0] = Q; go.Y[1] = K; go.Y[2] = V; go.Y[3] = H;
    go.bias[0] = (const float*)d_in[3 + L * 10 + 1];
    go.bias[1] = (const float*)d_in[3 + L * 10 + 3];
    go.bias[2] = (const float*)d_in[3 + L * 10 + 5];
    go.bias[3] = (const float*)d_in[3 + L * 10 + 7];
    gemm_proj<<<dim3((N + 63) / 64, 4), 256, 0, stream>>>(Xb, WT + L * 4 * 16384, go, N);

    node_attn<<<(N + 7) / 8, 256, 0, stream>>>(rowptr, adj, Q, K, V, H, N);

    hipMemsetAsync(bnsum, 0, 2 * 128 * 4, stream);       // bnsum + bnsq
    bn_stats<<<128, 256, 0, stream>>>(H, bnsum, bnsq, N);
    bn_finalize<<<1, 128, 0, stream>>>(bnsum, bnsq,
        (const float*)d_in[3 + L * 10 + 8],
        (const float*)d_in[3 + L * 10 + 9],
        scale, shift, N);

    if (L < 2) {
      bn_apply_relu<<<(N * 128 / 4 + 255) / 256, 256, 0, stream>>>(H, scale, shift, Xb, N * 128);
    } else {
      pool_linear<<<G, 256, 0, stream>>>(H, scale, shift, batch, Wlin, blin,
                                         (float*)d_out, N);
    }
  }
}

// Round 6
// 651.131 us; speedup vs baseline: 4.5352x; 1.1018x over previous
//
#include <hip/hip_runtime.h>

#define N_NODES 50000
#define N_EDGES 400000
#define DH 128
#define N_GRAPHS 256

#define SCAN_CHUNK 512
#define N_CHUNKS ((N_NODES + SCAN_CHUNK - 1) / SCAN_CHUNK)   // 98

typedef __bf16 bf16x8 __attribute__((ext_vector_type(8)));
typedef float f32x4 __attribute__((ext_vector_type(4)));
typedef _Float16 f16x4 __attribute__((ext_vector_type(4)));

#define DEV __device__ __forceinline__

DEV unsigned short f2bf(float f) {
  union { float f; unsigned int i; } v; v.f = f;
  unsigned int x = v.i;
  unsigned int r = (x + 0x7fffu + ((x >> 16) & 1u)) >> 16;
  return (unsigned short)r;
}

// ---------------- weight repack: WT[o*128+i] = bf16(W[i*128+o]) --------------
struct WPtrs { const float* w[12]; };

__global__ void repack_kernel(WPtrs wp, unsigned short* __restrict__ WT) {
  int mat = blockIdx.y;
  int idx = blockIdx.x * 256 + threadIdx.x;   // 0..16383
  int i = idx >> 7, o = idx & 127;
  WT[mat * 16384 + o * 128 + i] = f2bf(wp.w[mat][i * 128 + o]);
}

// ---------------- fp32 -> bf16 convert (layer-0 x) ---------------------------
__global__ void f32_to_bf16(const float* __restrict__ in, unsigned short* __restrict__ out,
                            int total4) {
  int i = blockIdx.x * 256 + threadIdx.x;
  if (i >= total4) return;
  float4 v = *reinterpret_cast<const float4*>(in + i * 4);
  ushort4 o;
  o.x = f2bf(v.x); o.y = f2bf(v.y); o.z = f2bf(v.z); o.w = f2bf(v.w);
  *reinterpret_cast<ushort4*>(out + i * 4) = o;
}

// ---------------- CSR build --------------------------------------------------
__global__ void deg_count(const int* __restrict__ ei, int* __restrict__ deg, int E) {
  int e = blockIdx.x * 256 + threadIdx.x;
  if (e < E) atomicAdd(&deg[ei[E + e]], 1);
}

__global__ __launch_bounds__(256) void scan_sum(const int* __restrict__ deg,
                                                int* __restrict__ partials, int N) {
  __shared__ int red[256];
  int b = blockIdx.x, t = threadIdx.x;
  int base = b * SCAN_CHUNK + t * 2;
  int s = 0;
  if (base + 1 < N) { int2 v = *reinterpret_cast<const int2*>(deg + base); s = v.x + v.y; }
  else if (base < N) s = deg[base];
  red[t] = s;
  __syncthreads();
  for (int off = 128; off; off >>= 1) {
    if (t < off) red[t] += red[t + off];
    __syncthreads();
  }
  if (t == 0) partials[b] = red[0];
}

__global__ __launch_bounds__(128) void scan_partials(int* __restrict__ partials) {
  __shared__ int s[128];
  int t = threadIdx.x;
  int v = (t < N_CHUNKS) ? partials[t] : 0;
  s[t] = v;
  __syncthreads();
  for (int off = 1; off < 128; off <<= 1) {
    int o = (t >= off) ? s[t - off] : 0;
    __syncthreads();
    s[t] += o;
    __syncthreads();
  }
  if (t < N_CHUNKS) partials[t] = s[t] - v;   // exclusive
}

__global__ __launch_bounds__(256) void scan_apply(const int* __restrict__ deg,
                                                  const int* __restrict__ partials,
                                                  int* __restrict__ rowptr,
                                                  int* __restrict__ cursor, int N, int E) {
  __shared__ int s[256];
  int b = blockIdx.x, t = threadIdx.x;
  int base = b * SCAN_CHUNK + t * 2;
  int d0 = 0, d1 = 0;
  if (base + 1 < N) { int2 v = *reinterpret_cast<const int2*>(deg + base); d0 = v.x; d1 = v.y; }
  else if (base < N) d0 = deg[base];
  int local = d0 + d1;
  s[t] = local;
  __syncthreads();
  for (int off = 1; off < 256; off <<= 1) {
    int o = (t >= off) ? s[t - off] : 0;
    __syncthreads();
    s[t] += o;
    __syncthreads();
  }
  int offp = partials[b] + s[t] - local;
  if (base < N)     { rowptr[base] = offp;          cursor[base] = offp; }
  if (base + 1 < N) { rowptr[base + 1] = offp + d0; cursor[base + 1] = offp + d0; }
  if (b == 0 && t == 0) rowptr[N] = E;
}

__global__ void csr_scatter(const int* __restrict__ ei, int* __restrict__ cursor,
                            int* __restrict__ adj, int E) {
  int e = blockIdx.x * 256 + threadIdx.x;
  if (e < E) {
    int dst = ei[E + e];
    int pos = atomicAdd(&cursor[dst], 1);
    adj[pos] = ei[e];
  }
}

// ---------------- fused projection GEMM: Y = X @ W + b  ----------------------
// proj 0 (Q) and 3 (S->H) write fp32; proj 1 (K) and 2 (V) write fp16.
struct GemmOut { void* Y[4]; const float* bias[4]; };

#define LDP 136   // padded LDS row stride (bf16 elems)

__global__ __launch_bounds__(256) void gemm_proj(
    const unsigned short* __restrict__ X,
    const unsigned short* __restrict__ WT4,
    GemmOut go, int N)
{
  __shared__ __align__(16) unsigned short xs[64 * LDP];
  __shared__ __align__(16) unsigned short wsh[128 * LDP];

  const int proj = blockIdx.y;
  const unsigned short* WT = WT4 + proj * 16384;
  const float* __restrict__ bias = go.bias[proj];

  const int t = threadIdx.x;
  const int rowBase = blockIdx.x * 64;

#pragma unroll
  for (int j = 0; j < 8; ++j) {
    int v = t + 256 * j;
    int o = v >> 4;
    int ig = (v & 15) * 8;
    uint4 val = *reinterpret_cast<const uint4*>(WT + o * 128 + ig);
    *reinterpret_cast<uint4*>(&wsh[o * LDP + ig]) = val;
  }
#pragma unroll
  for (int j = 0; j < 4; ++j) {
    int v = t + 256 * j;
    int r = v >> 4;
    int ig = (v & 15) * 8;
    int grow = rowBase + r;
    uint4 val = make_uint4(0u, 0u, 0u, 0u);
    if (grow < N) val = *reinterpret_cast<const uint4*>(X + grow * 128 + ig);
    *reinterpret_cast<uint4*>(&xs[r * LDP + ig]) = val;
  }
  __syncthreads();

  const int wave = t >> 6;
  const int lane = t & 63;
  const int ln16 = lane & 15;
  const int quad = lane >> 4;
  const int r0 = wave * 16;

  f32x4 acc[8] = {};

#pragma unroll
  for (int kk = 0; kk < 4; ++kk) {
    bf16x8 a = *reinterpret_cast<const bf16x8*>(&xs[(r0 + ln16) * LDP + kk * 32 + quad * 8]);
#pragma unroll
    for (int ct = 0; ct < 8; ++ct) {
      bf16x8 b = *reinterpret_cast<const bf16x8*>(&wsh[(ct * 16 + ln16) * LDP + kk * 32 + quad * 8]);
      acc[ct] = __builtin_amdgcn_mfma_f32_16x16x32_bf16(a, b, acc[ct], 0, 0, 0);
    }
  }

  const bool asHalf = (proj == 1) || (proj == 2);
  float* __restrict__ Yf = (float*)go.Y[proj];
  _Float16* __restrict__ Yh = (_Float16*)go.Y[proj];

#pragma unroll
  for (int ct = 0; ct < 8; ++ct) {
    int col = ct * 16 + ln16;
    float bv = bias[col];
#pragma unroll
    for (int reg = 0; reg < 4; ++reg) {
      int grow = rowBase + r0 + quad * 4 + reg;
      if (grow < N) {
        float v = acc[ct][reg] + bv;
        if (asHalf) Yh[grow * 128 + col] = (_Float16)v;
        else        Yf[grow * 128 + col] = v;
      }
    }
  }
}

// ---------------- fused per-node attention (gather, online softmax) ----------
// 32 lanes per dst node; K/V gathered as fp16 (8 B/lane); unroll 2 edges.
__global__ __launch_bounds__(256) void node_attn(
    const int* __restrict__ rowptr, const int* __restrict__ adj,
    const float* __restrict__ Q, const _Float16* __restrict__ K,
    const _Float16* __restrict__ V, float* __restrict__ H, int N)
{
  int n = blockIdx.x * 8 + (threadIdx.x >> 5);
  int lane = threadIdx.x & 31;
  if (n >= N) return;
  int p0 = rowptr[n], p1 = rowptr[n + 1];

  float4 q = *reinterpret_cast<const float4*>(Q + n * 128 + lane * 4);
  float m = -INFINITY, s = 0.f;
  float4 acc = make_float4(0.f, 0.f, 0.f, 0.f);

  int p = p0;
  for (; p + 1 < p1; p += 2) {
    int s0 = adj[p], s1 = adj[p + 1];
    f16x4 k0 = *reinterpret_cast<const f16x4*>(K + s0 * 128 + lane * 4);
    f16x4 k1 = *reinterpret_cast<const f16x4*>(K + s1 * 128 + lane * 4);
    float d0 = q.x * (float)k0.x + q.y * (float)k0.y + q.z * (float)k0.z + q.w * (float)k0.w;
    float d1 = q.x * (float)k1.x + q.y * (float)k1.y + q.z * (float)k1.z + q.w * (float)k1.w;
#pragma unroll
    for (int off = 16; off; off >>= 1) {
      d0 += __shfl_xor(d0, off, 32);
      d1 += __shfl_xor(d1, off, 32);
    }
    float l0 = d0 * 0.08838834764831845f;
    float l1 = d1 * 0.08838834764831845f;
    float mn = fmaxf(m, fmaxf(l0, l1));
    float sc = __expf(m - mn);
    float w0 = __expf(l0 - mn);
    float w1 = __expf(l1 - mn);
    f16x4 v0 = *reinterpret_cast<const f16x4*>(V + s0 * 128 + lane * 4);
    f16x4 v1 = *reinterpret_cast<const f16x4*>(V + s1 * 128 + lane * 4);
    acc.x = acc.x * sc + w0 * (float)v0.x + w1 * (float)v1.x;
    acc.y = acc.y * sc + w0 * (float)v0.y + w1 * (float)v1.y;
    acc.z = acc.z * sc + w0 * (float)v0.z + w1 * (float)v1.z;
    acc.w = acc.w * sc + w0 * (float)v0.w + w1 * (float)v1.w;
    s = s * sc + w0 + w1;
    m = mn;
  }
  if (p < p1) {
    int s0 = adj[p];
    f16x4 k0 = *reinterpret_cast<const f16x4*>(K + s0 * 128 + lane * 4);
    float d0 = q.x * (float)k0.x + q.y * (float)k0.y + q.z * (float)k0.z + q.w * (float)k0.w;
#pragma unroll
    for (int off = 16; off; off >>= 1) d0 += __shfl_xor(d0, off, 32);
    float l0 = d0 * 0.08838834764831845f;
    float mn = fmaxf(m, l0);
    float sc = __expf(m - mn);
    float w0 = __expf(l0 - mn);
    f16x4 v0 = *reinterpret_cast<const f16x4*>(V + s0 * 128 + lane * 4);
    acc.x = acc.x * sc + w0 * (float)v0.x;
    acc.y = acc.y * sc + w0 * (float)v0.y;
    acc.z = acc.z * sc + w0 * (float)v0.z;
    acc.w = acc.w * sc + w0 * (float)v0.w;
    s = s * sc + w0;
    m = mn;
  }

  float inv = 1.0f / (s + 1e-16f);
  float4 h = *reinterpret_cast<const float4*>(H + n * 128 + lane * 4);
  h.x += acc.x * inv;
  h.y += acc.y * inv;
  h.z += acc.z * inv;
  h.w += acc.w * inv;
  *reinterpret_cast<float4*>(H + n * 128 + lane * 4) = h;
}

// ---------------- batchnorm stats --------------------------------------------
__global__ __launch_bounds__(256) void bn_stats(
    const float* __restrict__ H, float* __restrict__ bnsum,
    float* __restrict__ bnsq, int N)
{
  __shared__ float red[512];
  int t = threadIdx.x;
  int f = t & 127, half = t >> 7;
  float s = 0.f, s2 = 0.f;
  for (int row = blockIdx.x * 2 + half; row < N; row += 256) {
    float v = H[row * 128 + f];
    s += v; s2 += v * v;
  }
  red[t] = s; red[256 + t] = s2;
  __syncthreads();
  if (t < 128) {
    s = red[t] + red[t + 128];
    s2 = red[256 + t] + red[384 + t];
    unsafeAtomicAdd(bnsum + f, s);
    unsafeAtomicAdd(bnsq + f, s2);
  }
}

__global__ void bn_finalize(const float* __restrict__ bnsum, const float* __restrict__ bnsq,
                            const float* __restrict__ gamma,
                            const float* __restrict__ beta,
                            float* __restrict__ scale, float* __restrict__ shift, int N)
{
  int f = threadIdx.x;   // 128 threads
  float mean = bnsum[f] / (float)N;
  float var = bnsq[f] / (float)N - mean * mean;
  var = fmaxf(var, 0.f);
  float sc = gamma[f] * rsqrtf(var + 1e-5f);
  scale[f] = sc;
  shift[f] = beta[f] - mean * sc;
}

// ---------------- apply BN + relu, write bf16 for next layer -----------------
__global__ void bn_apply_relu(const float* __restrict__ H, const float* __restrict__ scale,
                              const float* __restrict__ shift, unsigned short* __restrict__ Xb,
                              int total)
{
  int i4 = (blockIdx.x * 256 + threadIdx.x) * 4;
  if (i4 >= total) return;
  int f = i4 & 127;
  float4 h = *reinterpret_cast<const float4*>(H + i4);
  float4 sc = *reinterpret_cast<const float4*>(scale + f);
  float4 sh = *reinterpret_cast<const float4*>(shift + f);
  ushort4 o;
  o.x = f2bf(fmaxf(h.x * sc.x + sh.x, 0.f));
  o.y = f2bf(fmaxf(h.y * sc.y + sh.y, 0.f));
  o.z = f2bf(fmaxf(h.z * sc.z + sh.z, 0.f));
  o.w = f2bf(fmaxf(h.w * sc.w + sh.w, 0.f));
  *reinterpret_cast<ushort4*>(Xb + i4) = o;
}

// ---------------- per-graph pool (BN+ReLU fused) + linear head ---------------
__global__ __launch_bounds__(256) void pool_linear(
    const float* __restrict__ H, const float* __restrict__ scale,
    const float* __restrict__ shift, const int* __restrict__ batch,
    const float* __restrict__ Wlin, const float* __restrict__ blin,
    float* __restrict__ out, int N)
{
  __shared__ float red[256];
  __shared__ float pool[128];
  int g = blockIdx.x;
  int t = threadIdx.x;

  int lo = 0, hi = N;
  while (lo < hi) { int mid = (lo + hi) >> 1; if (batch[mid] < g) lo = mid + 1; else hi = mid; }
  int start = lo;
  hi = N;
  while (lo < hi) { int mid = (lo + hi) >> 1; if (batch[mid] < g + 1) lo = mid + 1; else hi = mid; }
  int end = lo;
  int cnt = end - start;

  int f = t & 127, half = t >> 7;
  float sc = scale[f], sh = shift[f];
  float s = 0.f;
  for (int row = start + half; row < end; row += 2)
    s += fmaxf(H[row * 128 + f] * sc + sh, 0.f);
  red[t] = s;
  __syncthreads();
  if (t < 128)
    pool[t] = (red[t] + red[t + 128]) / fmaxf((float)cnt, 1.f);
  __syncthreads();

  if (t < 20) {
    float acc = 0.f;
#pragma unroll 4
    for (int i = 0; i < 128; ++i)
      acc += pool[i] * Wlin[i * 20 + t];
    out[g * 20 + t] = acc + blin[t];
  }
}

// =============================================================================
extern "C" void kernel_launch(void* const* d_in, const int* in_sizes, int n_in,
                              void* d_out, int out_size, void* d_ws, size_t ws_size,
                              hipStream_t stream)
{
  const int N = N_NODES, E = N_EDGES, G = N_GRAPHS;

  const float* x = (const float*)d_in[0];
  const int* ei = (const int*)d_in[1];
  const int* batch = (const int*)d_in[2];
  const float* Wlin = (const float*)d_in[33];
  const float* blin = (const float*)d_in[34];

  char* ws = (char*)d_ws;
  size_t off = 0;
  auto alloc = [&](size_t bytes) -> void* {
    void* p = ws + off;
    off = (off + bytes + 255) & ~(size_t)255;
    return p;
  };
  unsigned short* WT = (unsigned short*)alloc(12 * 16384 * sizeof(unsigned short));
  float* Q      = (float*)alloc((size_t)N * 128 * 4);
  _Float16* Kh  = (_Float16*)alloc((size_t)N * 128 * 2);
  _Float16* Vh  = (_Float16*)alloc((size_t)N * 128 * 2);
  float* H      = (float*)alloc((size_t)N * 128 * 4);
  int* deg      = (int*)alloc((size_t)N * 4);
  int* rowptr   = (int*)alloc((size_t)(N + 1) * 4);
  int* cursor   = (int*)alloc((size_t)N * 4);
  int* adj      = (int*)alloc((size_t)E * 4);
  int* partials = (int*)alloc((size_t)N_CHUNKS * 4);
  float* bnsum  = (float*)alloc(128 * 4);       // bnsq contiguous after
  float* bnsq   = (float*)alloc(128 * 4);
  float* scale  = (float*)alloc(128 * 4);
  float* shift  = (float*)alloc(128 * 4);
  unsigned short* Xb = (unsigned short*)alloc((size_t)N * 128 * 2);

  // ---- one-time per launch: weight repack, x->bf16, CSR build ----
  WPtrs wp;
  for (int L = 0; L < 3; ++L) {
    wp.w[L * 4 + 0] = (const float*)d_in[3 + L * 10 + 0];  // Wq
    wp.w[L * 4 + 1] = (const float*)d_in[3 + L * 10 + 2];  // Wk
    wp.w[L * 4 + 2] = (const float*)d_in[3 + L * 10 + 4];  // Wv
    wp.w[L * 4 + 3] = (const float*)d_in[3 + L * 10 + 6];  // Ws
  }
  repack_kernel<<<dim3(64, 12), 256, 0, stream>>>(wp, WT);
  f32_to_bf16<<<(N * 128 / 4 + 255) / 256, 256, 0, stream>>>(x, Xb, N * 128 / 4);

  hipMemsetAsync(deg, 0, (size_t)N * 4, stream);
  deg_count<<<(E + 255) / 256, 256, 0, stream>>>(ei, deg, E);
  scan_sum<<<N_CHUNKS, 256, 0, stream>>>(deg, partials, N);
  scan_partials<<<1, 128, 0, stream>>>(partials);
  scan_apply<<<N_CHUNKS, 256, 0, stream>>>(deg, partials, rowptr, cursor, N, E);
  csr_scatter<<<(E + 255) / 256, 256, 0, stream>>>(ei, cursor, adj, E);

  for (int L = 0; L < 3; ++L) {
    GemmOut go;
    go.Y[0] = Q; go.Y[1] = Kh; go.Y[2] = Vh; go.Y[3] = H;
    go.bias[0] = (const float*)d_in[3 + L * 10 + 1];
    go.bias[1] = (const float*)d_in[3 + L * 10 + 3];
    go.bias[2] = (const float*)d_in[3 + L * 10 + 5];
    go.bias[3] = (const float*)d_in[3 + L * 10 + 7];
    gemm_proj<<<dim3((N + 63) / 64, 4), 256, 0, stream>>>(Xb, WT + L * 4 * 16384, go, N);

    node_attn<<<(N + 7) / 8, 256, 0, stream>>>(rowptr, adj, Q, Kh, Vh, H, N);

    hipMemsetAsync(bnsum, 0, 2 * 128 * 4, stream);       // bnsum + bnsq
    bn_stats<<<128, 256, 0, stream>>>(H, bnsum, bnsq, N);
    bn_finalize<<<1, 128, 0, stream>>>(bnsum, bnsq,
        (const float*)d_in[3 + L * 10 + 8],
        (const float*)d_in[3 + L * 10 + 9],
        scale, shift, N);

    if (L < 2) {
      bn_apply_relu<<<(N * 128 / 4 + 255) / 256, 256, 0, stream>>>(H, scale, shift, Xb, N * 128);
    } else {
      pool_linear<<<G, 256, 0, stream>>>(H, scale, shift, batch, Wlin, blin,
                                         (float*)d_out, N);
    }
  }
}

// Round 7
// 636.806 us; speedup vs baseline: 4.6372x; 1.0225x over previous
//
#include <hip/hip_runtime.h>

#define N_NODES 50000
#define N_EDGES 400000
#define DH 128
#define N_GRAPHS 256

#define SCAN_CHUNK 512
#define N_CHUNKS ((N_NODES + SCAN_CHUNK - 1) / SCAN_CHUNK)   // 98

typedef __bf16 bf16x8 __attribute__((ext_vector_type(8)));
typedef float f32x4 __attribute__((ext_vector_type(4)));
typedef _Float16 f16x4 __attribute__((ext_vector_type(4)));

#define DEV __device__ __forceinline__

DEV unsigned short f2bf(float f) {
  union { float f; unsigned int i; } v; v.f = f;
  unsigned int x = v.i;
  unsigned int r = (x + 0x7fffu + ((x >> 16) & 1u)) >> 16;
  return (unsigned short)r;
}

// ---- weight repack into MFMA B-fragment order ------------------------------
// WB[mat][kk][ct][lane][j] = bf16(W[i=kk*32+(lane>>4)*8+j][o=ct*16+(lane&15)])
// so a wave's B-fragment load for (kk,ct) is 64 consecutive 16B units.
struct WPtrs { const float* w[12]; };

__global__ void repack_kernel(WPtrs wp, unsigned short* __restrict__ WB) {
  int mat = blockIdx.y;
  int m = blockIdx.x * 256 + threadIdx.x;   // 0..16383
  int j = m & 7;
  int lane = (m >> 3) & 63;
  int ct = (m >> 9) & 7;
  int kk = m >> 12;
  int i = kk * 32 + (lane >> 4) * 8 + j;
  int o = ct * 16 + (lane & 15);
  WB[mat * 16384 + m] = f2bf(wp.w[mat][i * 128 + o]);
}

// ---------------- fp32 -> bf16 convert (layer-0 x) ---------------------------
__global__ void f32_to_bf16(const float* __restrict__ in, unsigned short* __restrict__ out,
                            int total4) {
  int i = blockIdx.x * 256 + threadIdx.x;
  if (i >= total4) return;
  float4 v = *reinterpret_cast<const float4*>(in + i * 4);
  ushort4 o;
  o.x = f2bf(v.x); o.y = f2bf(v.y); o.z = f2bf(v.z); o.w = f2bf(v.w);
  *reinterpret_cast<ushort4*>(out + i * 4) = o;
}

// ---------------- CSR build --------------------------------------------------
__global__ void deg_count(const int* __restrict__ ei, int* __restrict__ deg, int E) {
  int e = blockIdx.x * 256 + threadIdx.x;
  if (e < E) atomicAdd(&deg[ei[E + e]], 1);
}

__global__ __launch_bounds__(256) void scan_sum(const int* __restrict__ deg,
                                                int* __restrict__ partials, int N) {
  __shared__ int red[256];
  int b = blockIdx.x, t = threadIdx.x;
  int base = b * SCAN_CHUNK + t * 2;
  int s = 0;
  if (base + 1 < N) { int2 v = *reinterpret_cast<const int2*>(deg + base); s = v.x + v.y; }
  else if (base < N) s = deg[base];
  red[t] = s;
  __syncthreads();
  for (int off = 128; off; off >>= 1) {
    if (t < off) red[t] += red[t + off];
    __syncthreads();
  }
  if (t == 0) partials[b] = red[0];
}

__global__ __launch_bounds__(128) void scan_partials(int* __restrict__ partials) {
  __shared__ int s[128];
  int t = threadIdx.x;
  int v = (t < N_CHUNKS) ? partials[t] : 0;
  s[t] = v;
  __syncthreads();
  for (int off = 1; off < 128; off <<= 1) {
    int o = (t >= off) ? s[t - off] : 0;
    __syncthreads();
    s[t] += o;
    __syncthreads();
  }
  if (t < N_CHUNKS) partials[t] = s[t] - v;   // exclusive
}

__global__ __launch_bounds__(256) void scan_apply(const int* __restrict__ deg,
                                                  const int* __restrict__ partials,
                                                  int* __restrict__ rowptr,
                                                  int* __restrict__ cursor, int N, int E) {
  __shared__ int s[256];
  int b = blockIdx.x, t = threadIdx.x;
  int base = b * SCAN_CHUNK + t * 2;
  int d0 = 0, d1 = 0;
  if (base + 1 < N) { int2 v = *reinterpret_cast<const int2*>(deg + base); d0 = v.x; d1 = v.y; }
  else if (base < N) d0 = deg[base];
  int local = d0 + d1;
  s[t] = local;
  __syncthreads();
  for (int off = 1; off < 256; off <<= 1) {
    int o = (t >= off) ? s[t - off] : 0;
    __syncthreads();
    s[t] += o;
    __syncthreads();
  }
  int offp = partials[b] + s[t] - local;
  if (base < N)     { rowptr[base] = offp;          cursor[base] = offp; }
  if (base + 1 < N) { rowptr[base + 1] = offp + d0; cursor[base + 1] = offp + d0; }
  if (b == 0 && t == 0) rowptr[N] = E;
}

__global__ void csr_scatter(const int* __restrict__ ei, int* __restrict__ cursor,
                            int* __restrict__ adj, int E) {
  int e = blockIdx.x * 256 + threadIdx.x;
  if (e < E) {
    int dst = ei[E + e];
    int pos = atomicAdd(&cursor[dst], 1);
    adj[pos] = ei[e];
  }
}

// ---------------- fused projection GEMM: Y = X @ W + b  ----------------------
// W read directly from global in B-fragment order (L2-resident, coalesced);
// only the X tile is staged in LDS. proj 0..2 (Q,K,V) write fp16; proj 3 fp32.
struct GemmOut { void* Y[4]; const float* bias[4]; };

#define LDP 136   // padded LDS row stride (bf16 elems)

__global__ __launch_bounds__(256) void gemm_proj(
    const unsigned short* __restrict__ X,
    const unsigned short* __restrict__ WB4,   // fragment-ordered, 4 mats x 16384
    GemmOut go, int N)
{
  __shared__ __align__(16) unsigned short xs[64 * LDP];

  const int proj = blockIdx.y;
  const unsigned short* __restrict__ WB = WB4 + proj * 16384;
  const float* __restrict__ bias = go.bias[proj];

  const int t = threadIdx.x;
  const int rowBase = blockIdx.x * 64;

  // stage X tile (64x128 bf16) into LDS, padded; zero-fill OOB rows
#pragma unroll
  for (int j = 0; j < 4; ++j) {
    int v = t + 256 * j;
    int r = v >> 4;
    int ig = (v & 15) * 8;
    int grow = rowBase + r;
    uint4 val = make_uint4(0u, 0u, 0u, 0u);
    if (grow < N) val = *reinterpret_cast<const uint4*>(X + grow * 128 + ig);
    *reinterpret_cast<uint4*>(&xs[r * LDP + ig]) = val;
  }
  __syncthreads();

  const int wave = t >> 6;
  const int lane = t & 63;
  const int ln16 = lane & 15;
  const int quad = lane >> 4;
  const int r0 = wave * 16;

  f32x4 acc[8] = {};

#pragma unroll
  for (int kk = 0; kk < 4; ++kk) {
    bf16x8 a = *reinterpret_cast<const bf16x8*>(&xs[(r0 + ln16) * LDP + kk * 32 + quad * 8]);
#pragma unroll
    for (int ct = 0; ct < 8; ++ct) {
      bf16x8 b = *reinterpret_cast<const bf16x8*>(WB + ((kk * 8 + ct) * 64 + lane) * 8);
      acc[ct] = __builtin_amdgcn_mfma_f32_16x16x32_bf16(a, b, acc[ct], 0, 0, 0);
    }
  }

  const bool asHalf = (proj < 3);
  float* __restrict__ Yf = (float*)go.Y[proj];
  _Float16* __restrict__ Yh = (_Float16*)go.Y[proj];

#pragma unroll
  for (int ct = 0; ct < 8; ++ct) {
    int col = ct * 16 + ln16;
    float bv = bias[col];
#pragma unroll
    for (int reg = 0; reg < 4; ++reg) {
      int grow = rowBase + r0 + quad * 4 + reg;
      if (grow < N) {
        float v = acc[ct][reg] + bv;
        if (asHalf) Yh[grow * 128 + col] = (_Float16)v;
        else        Yf[grow * 128 + col] = v;
      }
    }
  }
}

// ---------------- fused per-node attention (gather, online softmax) ----------
__global__ __launch_bounds__(256) void node_attn(
    const int* __restrict__ rowptr, const int* __restrict__ adj,
    const _Float16* __restrict__ Q, const _Float16* __restrict__ K,
    const _Float16* __restrict__ V, float* __restrict__ H, int N)
{
  int n = blockIdx.x * 8 + (threadIdx.x >> 5);
  int lane = threadIdx.x & 31;
  if (n >= N) return;
  int p0 = rowptr[n], p1 = rowptr[n + 1];

  f16x4 qh = *reinterpret_cast<const f16x4*>(Q + n * 128 + lane * 4);
  float4 q = make_float4((float)qh.x, (float)qh.y, (float)qh.z, (float)qh.w);
  float m = -INFINITY, s = 0.f;
  float4 acc = make_float4(0.f, 0.f, 0.f, 0.f);

  int p = p0;
  for (; p + 1 < p1; p += 2) {
    int s0 = adj[p], s1 = adj[p + 1];
    f16x4 k0 = *reinterpret_cast<const f16x4*>(K + s0 * 128 + lane * 4);
    f16x4 k1 = *reinterpret_cast<const f16x4*>(K + s1 * 128 + lane * 4);
    float d0 = q.x * (float)k0.x + q.y * (float)k0.y + q.z * (float)k0.z + q.w * (float)k0.w;
    float d1 = q.x * (float)k1.x + q.y * (float)k1.y + q.z * (float)k1.z + q.w * (float)k1.w;
#pragma unroll
    for (int off = 16; off; off >>= 1) {
      d0 += __shfl_xor(d0, off, 32);
      d1 += __shfl_xor(d1, off, 32);
    }
    float l0 = d0 * 0.08838834764831845f;
    float l1 = d1 * 0.08838834764831845f;
    float mn = fmaxf(m, fmaxf(l0, l1));
    float sc = __expf(m - mn);
    float w0 = __expf(l0 - mn);
    float w1 = __expf(l1 - mn);
    f16x4 v0 = *reinterpret_cast<const f16x4*>(V + s0 * 128 + lane * 4);
    f16x4 v1 = *reinterpret_cast<const f16x4*>(V + s1 * 128 + lane * 4);
    acc.x = acc.x * sc + w0 * (float)v0.x + w1 * (float)v1.x;
    acc.y = acc.y * sc + w0 * (float)v0.y + w1 * (float)v1.y;
    acc.z = acc.z * sc + w0 * (float)v0.z + w1 * (float)v1.z;
    acc.w = acc.w * sc + w0 * (float)v0.w + w1 * (float)v1.w;
    s = s * sc + w0 + w1;
    m = mn;
  }
  if (p < p1) {
    int s0 = adj[p];
    f16x4 k0 = *reinterpret_cast<const f16x4*>(K + s0 * 128 + lane * 4);
    float d0 = q.x * (float)k0.x + q.y * (float)k0.y + q.z * (float)k0.z + q.w * (float)k0.w;
#pragma unroll
    for (int off = 16; off; off >>= 1) d0 += __shfl_xor(d0, off, 32);
    float l0 = d0 * 0.08838834764831845f;
    float mn = fmaxf(m, l0);
    float sc = __expf(m - mn);
    float w0 = __expf(l0 - mn);
    f16x4 v0 = *reinterpret_cast<const f16x4*>(V + s0 * 128 + lane * 4);
    acc.x = acc.x * sc + w0 * (float)v0.x;
    acc.y = acc.y * sc + w0 * (float)v0.y;
    acc.z = acc.z * sc + w0 * (float)v0.z;
    acc.w = acc.w * sc + w0 * (float)v0.w;
    s = s * sc + w0;
    m = mn;
  }

  float inv = 1.0f / (s + 1e-16f);
  float4 h = *reinterpret_cast<const float4*>(H + n * 128 + lane * 4);
  h.x += acc.x * inv;
  h.y += acc.y * inv;
  h.z += acc.z * inv;
  h.w += acc.w * inv;
  *reinterpret_cast<float4*>(H + n * 128 + lane * 4) = h;
}

// ---------------- batchnorm stats --------------------------------------------
__global__ __launch_bounds__(256) void bn_stats(
    const float* __restrict__ H, float* __restrict__ bnsum,
    float* __restrict__ bnsq, int N)
{
  __shared__ float red[512];
  int t = threadIdx.x;
  int f = t & 127, half = t >> 7;
  float s = 0.f, s2 = 0.f;
  for (int row = blockIdx.x * 2 + half; row < N; row += 256) {
    float v = H[row * 128 + f];
    s += v; s2 += v * v;
  }
  red[t] = s; red[256 + t] = s2;
  __syncthreads();
  if (t < 128) {
    s = red[t] + red[t + 128];
    s2 = red[256 + t] + red[384 + t];
    unsafeAtomicAdd(bnsum + f, s);
    unsafeAtomicAdd(bnsq + f, s2);
  }
}

__global__ void bn_finalize(const float* __restrict__ bnsum, const float* __restrict__ bnsq,
                            const float* __restrict__ gamma,
                            const float* __restrict__ beta,
                            float* __restrict__ scale, float* __restrict__ shift, int N)
{
  int f = threadIdx.x;   // 128 threads
  float mean = bnsum[f] / (float)N;
  float var = bnsq[f] / (float)N - mean * mean;
  var = fmaxf(var, 0.f);
  float sc = gamma[f] * rsqrtf(var + 1e-5f);
  scale[f] = sc;
  shift[f] = beta[f] - mean * sc;
}

// ---------------- apply BN + relu, write bf16 for next layer -----------------
__global__ void bn_apply_relu(const float* __restrict__ H, const float* __restrict__ scale,
                              const float* __restrict__ shift, unsigned short* __restrict__ Xb,
                              int total)
{
  int i4 = (blockIdx.x * 256 + threadIdx.x) * 4;
  if (i4 >= total) return;
  int f = i4 & 127;
  float4 h = *reinterpret_cast<const float4*>(H + i4);
  float4 sc = *reinterpret_cast<const float4*>(scale + f);
  float4 sh = *reinterpret_cast<const float4*>(shift + f);
  ushort4 o;
  o.x = f2bf(fmaxf(h.x * sc.x + sh.x, 0.f));
  o.y = f2bf(fmaxf(h.y * sc.y + sh.y, 0.f));
  o.z = f2bf(fmaxf(h.z * sc.z + sh.z, 0.f));
  o.w = f2bf(fmaxf(h.w * sc.w + sh.w, 0.f));
  *reinterpret_cast<ushort4*>(Xb + i4) = o;
}

// ---------------- per-graph pool (BN+ReLU fused) + linear head ---------------
__global__ __launch_bounds__(256) void pool_linear(
    const float* __restrict__ H, const float* __restrict__ scale,
    const float* __restrict__ shift, const int* __restrict__ batch,
    const float* __restrict__ Wlin, const float* __restrict__ blin,
    float* __restrict__ out, int N)
{
  __shared__ float red[256];
  __shared__ float pool[128];
  int g = blockIdx.x;
  int t = threadIdx.x;

  int lo = 0, hi = N;
  while (lo < hi) { int mid = (lo + hi) >> 1; if (batch[mid] < g) lo = mid + 1; else hi = mid; }
  int start = lo;
  hi = N;
  while (lo < hi) { int mid = (lo + hi) >> 1; if (batch[mid] < g + 1) lo = mid + 1; else hi = mid; }
  int end = lo;
  int cnt = end - start;

  int f = t & 127, half = t >> 7;
  float sc = scale[f], sh = shift[f];
  float s = 0.f;
  for (int row = start + half; row < end; row += 2)
    s += fmaxf(H[row * 128 + f] * sc + sh, 0.f);
  red[t] = s;
  __syncthreads();
  if (t < 128)
    pool[t] = (red[t] + red[t + 128]) / fmaxf((float)cnt, 1.f);
  __syncthreads();

  if (t < 20) {
    float acc = 0.f;
#pragma unroll 4
    for (int i = 0; i < 128; ++i)
      acc += pool[i] * Wlin[i * 20 + t];
    out[g * 20 + t] = acc + blin[t];
  }
}

// =============================================================================
extern "C" void kernel_launch(void* const* d_in, const int* in_sizes, int n_in,
                              void* d_out, int out_size, void* d_ws, size_t ws_size,
                              hipStream_t stream)
{
  const int N = N_NODES, E = N_EDGES, G = N_GRAPHS;

  const float* x = (const float*)d_in[0];
  const int* ei = (const int*)d_in[1];
  const int* batch = (const int*)d_in[2];
  const float* Wlin = (const float*)d_in[33];
  const float* blin = (const float*)d_in[34];

  char* ws = (char*)d_ws;
  size_t off = 0;
  auto alloc = [&](size_t bytes) -> void* {
    void* p = ws + off;
    off = (off + bytes + 255) & ~(size_t)255;
    return p;
  };
  unsigned short* WB = (unsigned short*)alloc(12 * 16384 * sizeof(unsigned short));
  _Float16* Qh  = (_Float16*)alloc((size_t)N * 128 * 2);
  _Float16* Kh  = (_Float16*)alloc((size_t)N * 128 * 2);
  _Float16* Vh  = (_Float16*)alloc((size_t)N * 128 * 2);
  float* H      = (float*)alloc((size_t)N * 128 * 4);
  int* deg      = (int*)alloc((size_t)N * 4);
  int* rowptr   = (int*)alloc((size_t)(N + 1) * 4);
  int* cursor   = (int*)alloc((size_t)N * 4);
  int* adj      = (int*)alloc((size_t)E * 4);
  int* partials = (int*)alloc((size_t)N_CHUNKS * 4);
  float* bnsum  = (float*)alloc(128 * 4);       // bnsq contiguous after
  float* bnsq   = (float*)alloc(128 * 4);
  float* scale  = (float*)alloc(128 * 4);
  float* shift  = (float*)alloc(128 * 4);
  unsigned short* Xb = (unsigned short*)alloc((size_t)N * 128 * 2);

  // ---- one-time per launch: weight repack, x->bf16, CSR build ----
  WPtrs wp;
  for (int L = 0; L < 3; ++L) {
    wp.w[L * 4 + 0] = (const float*)d_in[3 + L * 10 + 0];  // Wq
    wp.w[L * 4 + 1] = (const float*)d_in[3 + L * 10 + 2];  // Wk
    wp.w[L * 4 + 2] = (const float*)d_in[3 + L * 10 + 4];  // Wv
    wp.w[L * 4 + 3] = (const float*)d_in[3 + L * 10 + 6];  // Ws
  }
  repack_kernel<<<dim3(64, 12), 256, 0, stream>>>(wp, WB);
  f32_to_bf16<<<(N * 128 / 4 + 255) / 256, 256, 0, stream>>>(x, Xb, N * 128 / 4);

  hipMemsetAsync(deg, 0, (size_t)N * 4, stream);
  deg_count<<<(E + 255) / 256, 256, 0, stream>>>(ei, deg, E);
  scan_sum<<<N_CHUNKS, 256, 0, stream>>>(deg, partials, N);
  scan_partials<<<1, 128, 0, stream>>>(partials);
  scan_apply<<<N_CHUNKS, 256, 0, stream>>>(deg, partials, rowptr, cursor, N, E);
  csr_scatter<<<(E + 255) / 256, 256, 0, stream>>>(ei, cursor, adj, E);

  for (int L = 0; L < 3; ++L) {
    GemmOut go;
    go.Y[0] = Qh; go.Y[1] = Kh; go.Y[2] = Vh; go.Y[3] = H;
    go.bias[0] = (const float*)d_in[3 + L * 10 + 1];
    go.bias[1] = (const float*)d_in[3 + L * 10 + 3];
    go.bias[2] = (const float*)d_in[3 + L * 10 + 5];
    go.bias[3] = (const float*)d_in[3 + L * 10 + 7];
    gemm_proj<<<dim3((N + 63) / 64, 4), 256, 0, stream>>>(Xb, WB + L * 4 * 16384, go, N);

    node_attn<<<(N + 7) / 8, 256, 0, stream>>>(rowptr, adj, Qh, Kh, Vh, H, N);

    hipMemsetAsync(bnsum, 0, 2 * 128 * 4, stream);       // bnsum + bnsq
    bn_stats<<<128, 256, 0, stream>>>(H, bnsum, bnsq, N);
    bn_finalize<<<1, 128, 0, stream>>>(bnsum, bnsq,
        (const float*)d_in[3 + L * 10 + 8],
        (const float*)d_in[3 + L * 10 + 9],
        scale, shift, N);

    if (L < 2) {
      bn_apply_relu<<<(N * 128 / 4 + 255) / 256, 256, 0, stream>>>(H, scale, shift, Xb, N * 128);
    } else {
      pool_linear<<<G, 256, 0, stream>>>(H, scale, shift, batch, Wlin, blin,
                                         (float*)d_out, N);
    }
  }
}